// Round 1
// baseline (830.856 us; speedup 1.0000x reference)
//
#include <hip/hip_runtime.h>

#define BB 2
#define CC 256
#define CQ 64
#define DD 32
#define HH 64
#define WW 192
#define HW (HH*WW)   // 12288

__device__ __forceinline__ float eluf(float v) {
    return v > 0.f ? v : (__expf(v) - 1.f);
}

// ---------------- q/k/v conv1x1 ----------------
// thread = (b, og[0..23], h, w4): 8 out-channels x 4 w per thread
__global__ __launch_bounds__(256) void k_qkv(
    const float* __restrict__ t_feat, const float* __restrict__ s_feat,
    const float* __restrict__ qw, const float* __restrict__ qb,
    const float* __restrict__ kw, const float* __restrict__ kb,
    const float* __restrict__ vw, const float* __restrict__ vb,
    float* __restrict__ qbuf, float* __restrict__ kbuf, float* __restrict__ vbuf)
{
    int n  = blockIdx.x*256 + threadIdx.x;        // 147456 total
    int w4 = n % 48;
    int h  = (n/48) % HH;
    int og = (n/(48*HH)) % 24;
    int b  = n/(48*HH*24);
    int w  = w4*4;
    const float* src; const float* wg; const float* bs; float* dst; int o0;
    if (og < 8)       { src=t_feat; wg=qw; bs=qb; dst=qbuf; o0=og*8; }
    else if (og < 16) { src=s_feat; wg=kw; bs=kb; dst=kbuf; o0=(og-8)*8; }
    else              { src=s_feat; wg=vw; bs=vb; dst=vbuf; o0=(og-16)*8; }

    float acc[8][4];
    #pragma unroll
    for (int j=0;j<8;++j){acc[j][0]=0.f;acc[j][1]=0.f;acc[j][2]=0.f;acc[j][3]=0.f;}
    const float* sp = src + (size_t)b*CC*HW + h*WW + w;
    for (int c=0;c<CC;++c) {
        float4 f = *(const float4*)(sp + (size_t)c*HW);
        #pragma unroll
        for (int j=0;j<8;++j) {
            float wv = wg[(o0+j)*CC + c];
            acc[j][0] += wv*f.x; acc[j][1] += wv*f.y;
            acc[j][2] += wv*f.z; acc[j][3] += wv*f.w;
        }
    }
    #pragma unroll
    for (int j=0;j<8;++j) {
        float bias = bs[o0+j];
        float4 o; o.x=acc[j][0]+bias; o.y=acc[j][1]+bias;
                  o.z=acc[j][2]+bias; o.w=acc[j][3]+bias;
        *(float4*)(dst + ((size_t)(b*CQ + o0 + j))*HW + h*WW + w) = o;
    }
}

// ---------------- cost = q . warp(k) / 8 ----------------
// one block per (b,h); K-row staged in LDS; thread = w
__global__ __launch_bounds__(192) void k_cost(
    const float* __restrict__ qbuf, const float* __restrict__ kbuf,
    const float* __restrict__ directs, const int* __restrict__ img_w_p,
    float* __restrict__ cost1)
{
    __shared__ float klds[CQ*WW];   // 48 KiB
    int bh = blockIdx.x; int b = bh / HH; int h = bh % HH;
    for (int i = threadIdx.x; i < CQ*WW; i += 192)
        klds[i] = kbuf[((size_t)(b*CQ + i/WW))*HW + h*WW + (i%WW)];
    __syncthreads();

    int w = threadIdx.x;
    int imw = img_w_p[0];
    float rel = (imw != 640) ? (640.0f / (float)imw) : 1.0f;
    float sf  = 0.01f * rel * directs[b] * (float)(WW-1);

    float p[DD]; int px0[DD]; float pfr[DD];
    #pragma unroll
    for (int d=0; d<DD; ++d) {
        float srcx = fminf(fmaxf((float)w + (float)d*sf, 0.f), (float)(WW-1));
        int x0 = (int)floorf(srcx);
        px0[d] = x0; pfr[d] = srcx - (float)x0; p[d] = 0.f;
    }
    const float* qp = qbuf + (size_t)b*CQ*HW + h*WW + w;
    for (int c=0;c<CQ;++c) {
        float qv = qp[(size_t)c*HW];
        const float* kr = klds + c*WW;
        #pragma unroll
        for (int d=0; d<DD; ++d) {
            int x0 = px0[d]; int x1 = min(x0+1, WW-1);
            float g0 = kr[x0], g1 = kr[x1];
            p[d] += qv * (g0 + pfr[d]*(g1-g0));
        }
    }
    float* cp = cost1 + (size_t)b*DD*HW + h*WW + w;
    #pragma unroll
    for (int d=0; d<DD; ++d) cp[(size_t)d*HW] = p[d]*0.125f;
}

// ---------------- softmax(cost) then agg_v = p . warp(v) ----------------
__global__ __launch_bounds__(192) void k_agg(
    const float* __restrict__ vbuf, const float* __restrict__ cost1,
    const float* __restrict__ directs, const int* __restrict__ img_w_p,
    float* __restrict__ aggv)
{
    __shared__ float vlds[CQ*WW];   // 48 KiB
    int bh = blockIdx.x; int b = bh / HH; int h = bh % HH;
    for (int i = threadIdx.x; i < CQ*WW; i += 192)
        vlds[i] = vbuf[((size_t)(b*CQ + i/WW))*HW + h*WW + (i%WW)];
    __syncthreads();

    int w = threadIdx.x;
    int imw = img_w_p[0];
    float rel = (imw != 640) ? (640.0f / (float)imw) : 1.0f;
    float sf  = 0.01f * rel * directs[b] * (float)(WW-1);

    float p[DD]; int px0[DD]; float pfr[DD];
    const float* cp = cost1 + (size_t)b*DD*HW + h*WW + w;
    float m = -1e30f;
    #pragma unroll
    for (int d=0; d<DD; ++d) { p[d] = cp[(size_t)d*HW]; m = fmaxf(m, p[d]); }
    float s = 0.f;
    #pragma unroll
    for (int d=0; d<DD; ++d) { p[d] = __expf(p[d]-m); s += p[d]; }
    float inv = 1.0f / s;
    #pragma unroll
    for (int d=0; d<DD; ++d) {
        p[d] *= inv;
        float srcx = fminf(fmaxf((float)w + (float)d*sf, 0.f), (float)(WW-1));
        int x0 = (int)floorf(srcx);
        px0[d] = x0; pfr[d] = srcx - (float)x0;
    }
    for (int c=0;c<CQ;++c) {
        const float* vr = vlds + c*WW;
        float a = 0.f;
        #pragma unroll
        for (int d=0; d<DD; ++d) {
            int x0 = px0[d]; int x1 = min(x0+1, WW-1);
            float g0 = vr[x0], g1 = vr[x1];
            a += p[d]*(g0 + pfr[d]*(g1-g0));
        }
        aggv[((size_t)(b*CQ+c))*HW + h*WW + w] = a;
    }
}

// ---------------- conv3x3 p1 on concat(q, agg_v), ELU ----------------
// thread = (b, o[0..63], h, w4): 4 consecutive w outputs
__global__ __launch_bounds__(256) void k_conv1(
    const float* __restrict__ qbuf, const float* __restrict__ aggv,
    const float* __restrict__ p1w, const float* __restrict__ p1b,
    float* __restrict__ h1)
{
    int n  = blockIdx.x*256 + threadIdx.x;   // 393216 total
    int w4 = n % 48;
    int h  = (n/48) % HH;
    int o  = (n/(48*HH)) % CQ;
    int b  = n/(48*HH*CQ);
    int w  = w4*4;
    float bias = p1b[o];
    float a0=bias, a1=bias, a2=bias, a3=bias;
    for (int ci=0; ci<128; ++ci) {
        const float* inp = (ci<CQ) ? qbuf : aggv;
        int cc = ci & (CQ-1);
        const float* wp = p1w + ((size_t)o*128 + ci)*9;
        const float* rbase = inp + ((size_t)(b*CQ+cc))*HW;
        #pragma unroll
        for (int kh=0; kh<3; ++kh) {
            int hh = h + kh - 1;
            if (hh < 0 || hh >= HH) continue;
            const float* rp = rbase + hh*WW;
            float4 mid = *(const float4*)(rp + w);
            float L = (w > 0)      ? rp[w-1] : 0.f;
            float R = (w+4 < WW)   ? rp[w+4] : 0.f;
            float w0 = wp[kh*3+0], w1 = wp[kh*3+1], w2 = wp[kh*3+2];
            a0 += w0*L     + w1*mid.x + w2*mid.y;
            a1 += w0*mid.x + w1*mid.y + w2*mid.z;
            a2 += w0*mid.y + w1*mid.z + w2*mid.w;
            a3 += w0*mid.z + w1*mid.w + w2*R;
        }
    }
    float4 o4; o4.x=eluf(a0); o4.y=eluf(a1); o4.z=eluf(a2); o4.w=eluf(a3);
    *(float4*)(h1 + ((size_t)(b*CQ+o))*HW + h*WW + w) = o4;
}

// ---------------- conv3x3 p2 + residual merge -> final cost (output 1) ----------------
__global__ __launch_bounds__(256) void k_conv2(
    const float* __restrict__ h1, const float* __restrict__ p2w, const float* __restrict__ p2b,
    const float* __restrict__ cost1, float* __restrict__ cost_out)
{
    int n  = blockIdx.x*256 + threadIdx.x;   // 196608 total
    int w4 = n % 48;
    int h  = (n/48) % HH;
    int o  = (n/(48*HH)) % DD;
    int b  = n/(48*HH*DD);
    int w  = w4*4;
    float bias = p2b[o];
    float a0=bias, a1=bias, a2=bias, a3=bias;
    for (int ci=0; ci<CQ; ++ci) {
        const float* wp = p2w + ((size_t)o*CQ + ci)*9;
        const float* rbase = h1 + ((size_t)(b*CQ+ci))*HW;
        #pragma unroll
        for (int kh=0; kh<3; ++kh) {
            int hh = h + kh - 1;
            if (hh < 0 || hh >= HH) continue;
            const float* rp = rbase + hh*WW;
            float4 mid = *(const float4*)(rp + w);
            float L = (w > 0)    ? rp[w-1] : 0.f;
            float R = (w+4 < WW) ? rp[w+4] : 0.f;
            float w0 = wp[kh*3+0], w1 = wp[kh*3+1], w2 = wp[kh*3+2];
            a0 += w0*L     + w1*mid.x + w2*mid.y;
            a1 += w0*mid.x + w1*mid.y + w2*mid.z;
            a2 += w0*mid.y + w1*mid.z + w2*mid.w;
            a3 += w0*mid.z + w1*mid.w + w2*R;
        }
    }
    size_t ofs = ((size_t)(b*DD+o))*HW + h*WW + w;
    float4 cv = *(const float4*)(cost1 + ofs);
    float4 out;
    out.x=(cv.x+a0)*0.5f; out.y=(cv.y+a1)*0.5f; out.z=(cv.z+a2)*0.5f; out.w=(cv.w+a3)*0.5f;
    *(float4*)(cost_out + ofs) = out;
}

// ---------------- softmax over D of final cost ----------------
__global__ __launch_bounds__(256) void k_sm2(
    const float* __restrict__ cost, float* __restrict__ nc2)
{
    int n = blockIdx.x*256 + threadIdx.x;  // 24576 total
    int hw = n % HW; int b = n / HW;
    const float* cp = cost + (size_t)b*DD*HW + hw;
    float p[DD]; float m = -1e30f;
    #pragma unroll
    for (int d=0; d<DD; ++d) { p[d] = cp[(size_t)d*HW]; m = fmaxf(m, p[d]); }
    float s = 0.f;
    #pragma unroll
    for (int d=0; d<DD; ++d) { p[d] = __expf(p[d]-m); s += p[d]; }
    float inv = 1.0f/s;
    float* op = nc2 + (size_t)b*DD*HW + hw;
    #pragma unroll
    for (int d=0; d<DD; ++d) op[(size_t)d*HW] = p[d]*inv;
}

// ---------------- final conv1x1 on concat(t_feat, nc2), ELU (output 0) ----------------
// thread = (b, og[0..63], h, w4): 4 out-channels x 4 w
__global__ __launch_bounds__(256) void k_final(
    const float* __restrict__ t_feat, const float* __restrict__ nc2,
    const float* __restrict__ rw, const float* __restrict__ rb,
    float* __restrict__ xout)
{
    int n  = blockIdx.x*256 + threadIdx.x;  // 393216 total
    int w4 = n % 48;
    int h  = (n/48) % HH;
    int og = (n/(48*HH)) % 64;
    int b  = n/(48*HH*64);
    int w  = w4*4; int o0 = og*4;
    float acc[4][4];
    #pragma unroll
    for (int j=0;j<4;++j){acc[j][0]=0.f;acc[j][1]=0.f;acc[j][2]=0.f;acc[j][3]=0.f;}
    const float* tp = t_feat + (size_t)b*CC*HW + h*WW + w;
    for (int c=0;c<CC;++c) {
        float4 f = *(const float4*)(tp + (size_t)c*HW);
        #pragma unroll
        for (int j=0;j<4;++j) {
            float wv = rw[(o0+j)*(CC+DD) + c];
            acc[j][0]+=wv*f.x; acc[j][1]+=wv*f.y; acc[j][2]+=wv*f.z; acc[j][3]+=wv*f.w;
        }
    }
    const float* np_ = nc2 + (size_t)b*DD*HW + h*WW + w;
    for (int d=0; d<DD; ++d) {
        float4 f = *(const float4*)(np_ + (size_t)d*HW);
        #pragma unroll
        for (int j=0;j<4;++j) {
            float wv = rw[(o0+j)*(CC+DD) + CC + d];
            acc[j][0]+=wv*f.x; acc[j][1]+=wv*f.y; acc[j][2]+=wv*f.z; acc[j][3]+=wv*f.w;
        }
    }
    #pragma unroll
    for (int j=0;j<4;++j) {
        float bias = rb[o0+j];
        float4 o; o.x=eluf(acc[j][0]+bias); o.y=eluf(acc[j][1]+bias);
                  o.z=eluf(acc[j][2]+bias); o.w=eluf(acc[j][3]+bias);
        *(float4*)(xout + ((size_t)(b*CC+o0+j))*HW + h*WW + w) = o;
    }
}

extern "C" void kernel_launch(void* const* d_in, const int* in_sizes, int n_in,
                              void* d_out, int out_size, void* d_ws, size_t ws_size,
                              hipStream_t stream)
{
    const float* t_feat = (const float*)d_in[0];
    const float* s_feat = (const float*)d_in[1];
    const float* directs= (const float*)d_in[2];
    const float* qw = (const float*)d_in[3];
    const float* qb = (const float*)d_in[4];
    const float* kw = (const float*)d_in[5];
    const float* kb = (const float*)d_in[6];
    const float* vw = (const float*)d_in[7];
    const float* vb = (const float*)d_in[8];
    const float* p1w= (const float*)d_in[9];
    const float* p1b= (const float*)d_in[10];
    const float* p2w= (const float*)d_in[11];
    const float* p2b= (const float*)d_in[12];
    const float* rw = (const float*)d_in[13];
    const float* rb = (const float*)d_in[14];
    const int* img_w= (const int*)d_in[15];

    // workspace layout (floats)
    float* ws    = (float*)d_ws;
    float* qbuf  = ws;                   // B*64*HW = 1572864
    float* kbuf  = qbuf  + 1572864;
    float* vbuf  = kbuf  + 1572864;
    float* aggv  = vbuf  + 1572864;
    float* cost1 = aggv  + 1572864;      // B*32*HW = 786432
    float* h1    = cost1 + 786432;       // 1572864
    float* nc2   = h1    + 1572864;      // 786432
    size_t need_bytes = (size_t)(1572864*4 + 786432*2 + 1572864) * sizeof(float);
    if (ws_size < need_bytes) return;    // fail visibly if workspace too small

    float* xout     = (float*)d_out;                  // [B,256,H,W]
    float* cost_out = xout + (size_t)BB*CC*HW;        // [B,32,H,W]

    k_qkv  <<<576,  256, 0, stream>>>(t_feat, s_feat, qw,qb,kw,kb,vw,vb, qbuf,kbuf,vbuf);
    k_cost <<<128,  192, 0, stream>>>(qbuf, kbuf, directs, img_w, cost1);
    k_agg  <<<128,  192, 0, stream>>>(vbuf, cost1, directs, img_w, aggv);
    k_conv1<<<1536, 256, 0, stream>>>(qbuf, aggv, p1w, p1b, h1);
    k_conv2<<<768,  256, 0, stream>>>(h1, p2w, p2b, cost1, cost_out);
    k_sm2  <<<96,   256, 0, stream>>>(cost_out, nc2);
    k_final<<<1536, 256, 0, stream>>>(t_feat, nc2, rw, rb, xout);
}

// Round 2
// 505.889 us; speedup vs baseline: 1.6424x; 1.6424x over previous
//
#include <hip/hip_runtime.h>

#define BB 2
#define CC 256
#define CQ 64
#define DD 32
#define HH 64
#define WW 192
#define HW (HH*WW)   // 12288

__device__ __forceinline__ float eluf(float v) {
    return v > 0.f ? v : (__expf(v) - 1.f);
}

// ---------------- q/k/v conv1x1 ----------------
// block-uniform og (weights become scalar loads); thread = 8 out-ch x 4 w
__global__ __launch_bounds__(256) void k_qkv(
    const float* __restrict__ t_feat, const float* __restrict__ s_feat,
    const float* __restrict__ qw, const float* __restrict__ qb,
    const float* __restrict__ kw, const float* __restrict__ kb,
    const float* __restrict__ vw, const float* __restrict__ vb,
    float* __restrict__ qbuf, float* __restrict__ kbuf, float* __restrict__ vbuf)
{
    int local = (blockIdx.x % 12)*256 + threadIdx.x;  // 0..3071
    int w4 = local % 48;
    int h  = local / 48;
    int bog = blockIdx.x / 12;    // 0..47
    int og  = bog % 24;
    int b   = bog / 24;
    int w   = w4*4;
    const float* src; const float* wg; const float* bs; float* dst; int o0;
    if (og < 8)       { src=t_feat; wg=qw; bs=qb; dst=qbuf; o0=og*8; }
    else if (og < 16) { src=s_feat; wg=kw; bs=kb; dst=kbuf; o0=(og-8)*8; }
    else              { src=s_feat; wg=vw; bs=vb; dst=vbuf; o0=(og-16)*8; }

    float acc[8][4];
    #pragma unroll
    for (int j=0;j<8;++j){acc[j][0]=0.f;acc[j][1]=0.f;acc[j][2]=0.f;acc[j][3]=0.f;}
    const float* sp = src + (size_t)b*CC*HW + h*WW + w;
    for (int c=0;c<CC;++c) {
        float4 f = *(const float4*)(sp + (size_t)c*HW);
        #pragma unroll
        for (int j=0;j<8;++j) {
            float wv = wg[(o0+j)*CC + c];
            acc[j][0] += wv*f.x; acc[j][1] += wv*f.y;
            acc[j][2] += wv*f.z; acc[j][3] += wv*f.w;
        }
    }
    #pragma unroll
    for (int j=0;j<8;++j) {
        float bias = bs[o0+j];
        float4 o; o.x=acc[j][0]+bias; o.y=acc[j][1]+bias;
                  o.z=acc[j][2]+bias; o.w=acc[j][3]+bias;
        *(float4*)(dst + ((size_t)(b*CQ + o0 + j))*HW + h*WW + w) = o;
    }
}

// ---------------- cost = q . warp(k) / 8 ----------------
__global__ __launch_bounds__(192) void k_cost(
    const float* __restrict__ qbuf, const float* __restrict__ kbuf,
    const float* __restrict__ directs, const int* __restrict__ img_w_p,
    float* __restrict__ cost1)
{
    __shared__ float klds[CQ*WW];   // 48 KiB
    int bh = blockIdx.x; int b = bh / HH; int h = bh % HH;
    for (int i = threadIdx.x; i < CQ*WW; i += 192)
        klds[i] = kbuf[((size_t)(b*CQ + i/WW))*HW + h*WW + (i%WW)];
    __syncthreads();

    int w = threadIdx.x;
    int imw = img_w_p[0];
    float rel = (imw != 640) ? (640.0f / (float)imw) : 1.0f;
    float sf  = 0.01f * rel * directs[b] * (float)(WW-1);

    float p[DD]; int px0[DD]; float pfr[DD];
    #pragma unroll
    for (int d=0; d<DD; ++d) {
        float srcx = fminf(fmaxf((float)w + (float)d*sf, 0.f), (float)(WW-1));
        int x0 = (int)floorf(srcx);
        px0[d] = x0; pfr[d] = srcx - (float)x0; p[d] = 0.f;
    }
    const float* qp = qbuf + (size_t)b*CQ*HW + h*WW + w;
    for (int c=0;c<CQ;++c) {
        float qv = qp[(size_t)c*HW];
        const float* kr = klds + c*WW;
        #pragma unroll
        for (int d=0; d<DD; ++d) {
            int x0 = px0[d]; int x1 = min(x0+1, WW-1);
            float g0 = kr[x0], g1 = kr[x1];
            p[d] += qv * (g0 + pfr[d]*(g1-g0));
        }
    }
    float* cp = cost1 + (size_t)b*DD*HW + h*WW + w;
    #pragma unroll
    for (int d=0; d<DD; ++d) cp[(size_t)d*HW] = p[d]*0.125f;
}

// ---------------- softmax(cost) then agg_v = p . warp(v) ----------------
__global__ __launch_bounds__(192) void k_agg(
    const float* __restrict__ vbuf, const float* __restrict__ cost1,
    const float* __restrict__ directs, const int* __restrict__ img_w_p,
    float* __restrict__ aggv)
{
    __shared__ float vlds[CQ*WW];   // 48 KiB
    int bh = blockIdx.x; int b = bh / HH; int h = bh % HH;
    for (int i = threadIdx.x; i < CQ*WW; i += 192)
        vlds[i] = vbuf[((size_t)(b*CQ + i/WW))*HW + h*WW + (i%WW)];
    __syncthreads();

    int w = threadIdx.x;
    int imw = img_w_p[0];
    float rel = (imw != 640) ? (640.0f / (float)imw) : 1.0f;
    float sf  = 0.01f * rel * directs[b] * (float)(WW-1);

    float p[DD]; int px0[DD]; float pfr[DD];
    const float* cp = cost1 + (size_t)b*DD*HW + h*WW + w;
    float m = -1e30f;
    #pragma unroll
    for (int d=0; d<DD; ++d) { p[d] = cp[(size_t)d*HW]; m = fmaxf(m, p[d]); }
    float s = 0.f;
    #pragma unroll
    for (int d=0; d<DD; ++d) { p[d] = __expf(p[d]-m); s += p[d]; }
    float inv = 1.0f / s;
    #pragma unroll
    for (int d=0; d<DD; ++d) {
        p[d] *= inv;
        float srcx = fminf(fmaxf((float)w + (float)d*sf, 0.f), (float)(WW-1));
        int x0 = (int)floorf(srcx);
        px0[d] = x0; pfr[d] = srcx - (float)x0;
    }
    for (int c=0;c<CQ;++c) {
        const float* vr = vlds + c*WW;
        float a = 0.f;
        #pragma unroll
        for (int d=0; d<DD; ++d) {
            int x0 = px0[d]; int x1 = min(x0+1, WW-1);
            float g0 = vr[x0], g1 = vr[x1];
            a += p[d]*(g0 + pfr[d]*(g1-g0));
        }
        aggv[((size_t)(b*CQ+c))*HW + h*WW + w] = a;
    }
}

// ---------------- conv3x3 p1 on concat(q, agg_v), ELU ----------------
// block-uniform o-group; thread = 8 out-ch x 4 w; loads shared across 8 o
__global__ __launch_bounds__(256) void k_conv1(
    const float* __restrict__ qbuf, const float* __restrict__ aggv,
    const float* __restrict__ p1w, const float* __restrict__ p1b,
    float* __restrict__ h1)
{
    int local = (blockIdx.x % 12)*256 + threadIdx.x;  // 0..3071
    int w4 = local % 48;
    int h  = local / 48;
    int bog = blockIdx.x / 12;     // 0..15
    int o0  = (bog & 7)*8;
    int b   = bog >> 3;
    int w   = w4*4;

    float acc[8][4];
    #pragma unroll
    for (int j=0;j<8;++j){ float bv = p1b[o0+j];
        acc[j][0]=bv;acc[j][1]=bv;acc[j][2]=bv;acc[j][3]=bv; }

    bool v0 = (h > 0), v2 = (h < HH-1);

    #pragma unroll
    for (int half=0; half<2; ++half) {
      const float* srcb = (half ? aggv : qbuf) + ((size_t)b*CQ)*HW;
      for (int cc=0; cc<CQ; ++cc) {
        int ci = half*CQ + cc;
        const float* rbase = srcb + (size_t)cc*HW;
        float4 mid[3]; float L[3], R[3];
        #pragma unroll
        for (int kh=0;kh<3;++kh){
          bool valid = (kh==1) || (kh==0 ? v0 : v2);
          if (valid) {
            const float* rp = rbase + (h+kh-1)*WW;
            mid[kh] = *(const float4*)(rp + w);
            L[kh] = (w>0)      ? rp[w-1] : 0.f;
            R[kh] = (w+4<WW)   ? rp[w+4] : 0.f;
          } else {
            mid[kh] = make_float4(0.f,0.f,0.f,0.f); L[kh]=0.f; R[kh]=0.f;
          }
        }
        #pragma unroll
        for (int j=0;j<8;++j){
          const float* wp = p1w + ((size_t)((o0+j)*128 + ci))*9;
          #pragma unroll
          for (int kh=0;kh<3;++kh){
            float w0=wp[kh*3], w1=wp[kh*3+1], w2=wp[kh*3+2];
            acc[j][0] += w0*L[kh]     + w1*mid[kh].x + w2*mid[kh].y;
            acc[j][1] += w0*mid[kh].x + w1*mid[kh].y + w2*mid[kh].z;
            acc[j][2] += w0*mid[kh].y + w1*mid[kh].z + w2*mid[kh].w;
            acc[j][3] += w0*mid[kh].z + w1*mid[kh].w + w2*R[kh];
          }
        }
      }
    }
    #pragma unroll
    for (int j=0;j<8;++j){
      float4 o4; o4.x=eluf(acc[j][0]); o4.y=eluf(acc[j][1]);
                 o4.z=eluf(acc[j][2]); o4.w=eluf(acc[j][3]);
      *(float4*)(h1 + ((size_t)(b*CQ+o0+j))*HW + h*WW + w) = o4;
    }
}

// ---------------- conv3x3 p2 + residual merge -> final cost (output 1) ----------------
__global__ __launch_bounds__(256) void k_conv2(
    const float* __restrict__ h1, const float* __restrict__ p2w, const float* __restrict__ p2b,
    const float* __restrict__ cost1, float* __restrict__ cost_out)
{
    int local = (blockIdx.x % 12)*256 + threadIdx.x;
    int w4 = local % 48;
    int h  = local / 48;
    int bog = blockIdx.x / 12;     // 0..7
    int o0  = (bog & 3)*8;
    int b   = bog >> 2;
    int w   = w4*4;

    float acc[8][4];
    #pragma unroll
    for (int j=0;j<8;++j){ float bv = p2b[o0+j];
        acc[j][0]=bv;acc[j][1]=bv;acc[j][2]=bv;acc[j][3]=bv; }

    bool v0 = (h > 0), v2 = (h < HH-1);
    const float* srcb = h1 + ((size_t)b*CQ)*HW;
    for (int ci=0; ci<CQ; ++ci) {
        const float* rbase = srcb + (size_t)ci*HW;
        float4 mid[3]; float L[3], R[3];
        #pragma unroll
        for (int kh=0;kh<3;++kh){
          bool valid = (kh==1) || (kh==0 ? v0 : v2);
          if (valid) {
            const float* rp = rbase + (h+kh-1)*WW;
            mid[kh] = *(const float4*)(rp + w);
            L[kh] = (w>0)      ? rp[w-1] : 0.f;
            R[kh] = (w+4<WW)   ? rp[w+4] : 0.f;
          } else {
            mid[kh] = make_float4(0.f,0.f,0.f,0.f); L[kh]=0.f; R[kh]=0.f;
          }
        }
        #pragma unroll
        for (int j=0;j<8;++j){
          const float* wp = p2w + ((size_t)((o0+j)*CQ + ci))*9;
          #pragma unroll
          for (int kh=0;kh<3;++kh){
            float w0=wp[kh*3], w1=wp[kh*3+1], w2=wp[kh*3+2];
            acc[j][0] += w0*L[kh]     + w1*mid[kh].x + w2*mid[kh].y;
            acc[j][1] += w0*mid[kh].x + w1*mid[kh].y + w2*mid[kh].z;
            acc[j][2] += w0*mid[kh].y + w1*mid[kh].z + w2*mid[kh].w;
            acc[j][3] += w0*mid[kh].z + w1*mid[kh].w + w2*R[kh];
          }
        }
    }
    #pragma unroll
    for (int j=0;j<8;++j){
        size_t ofs = ((size_t)(b*DD+o0+j))*HW + h*WW + w;
        float4 cv = *(const float4*)(cost1 + ofs);
        float4 out;
        out.x=(cv.x+acc[j][0])*0.5f; out.y=(cv.y+acc[j][1])*0.5f;
        out.z=(cv.z+acc[j][2])*0.5f; out.w=(cv.w+acc[j][3])*0.5f;
        *(float4*)(cost_out + ofs) = out;
    }
}

// ---------------- softmax over D of final cost ----------------
__global__ __launch_bounds__(256) void k_sm2(
    const float* __restrict__ cost, float* __restrict__ nc2)
{
    int n = blockIdx.x*256 + threadIdx.x;  // 24576 total
    int hw = n % HW; int b = n / HW;
    const float* cp = cost + (size_t)b*DD*HW + hw;
    float p[DD]; float m = -1e30f;
    #pragma unroll
    for (int d=0; d<DD; ++d) { p[d] = cp[(size_t)d*HW]; m = fmaxf(m, p[d]); }
    float s = 0.f;
    #pragma unroll
    for (int d=0; d<DD; ++d) { p[d] = __expf(p[d]-m); s += p[d]; }
    float inv = 1.0f/s;
    float* op = nc2 + (size_t)b*DD*HW + hw;
    #pragma unroll
    for (int d=0; d<DD; ++d) op[(size_t)d*HW] = p[d]*inv;
}

// ---------------- final conv1x1 on concat(t_feat, nc2), ELU (output 0) ----------------
// block-uniform o-group; thread = 8 out-ch x 4 w
__global__ __launch_bounds__(256) void k_final(
    const float* __restrict__ t_feat, const float* __restrict__ nc2,
    const float* __restrict__ rw, const float* __restrict__ rb,
    float* __restrict__ xout)
{
    int local = (blockIdx.x % 12)*256 + threadIdx.x;
    int w4 = local % 48;
    int h  = local / 48;
    int bog = blockIdx.x / 12;     // 0..63
    int o0  = (bog & 31)*8;
    int b   = bog >> 5;
    int w   = w4*4;

    float acc[8][4];
    #pragma unroll
    for (int j=0;j<8;++j){acc[j][0]=0.f;acc[j][1]=0.f;acc[j][2]=0.f;acc[j][3]=0.f;}
    const float* tp = t_feat + (size_t)b*CC*HW + h*WW + w;
    for (int c=0;c<CC;++c) {
        float4 f = *(const float4*)(tp + (size_t)c*HW);
        #pragma unroll
        for (int j=0;j<8;++j) {
            float wv = rw[(o0+j)*(CC+DD) + c];
            acc[j][0]+=wv*f.x; acc[j][1]+=wv*f.y; acc[j][2]+=wv*f.z; acc[j][3]+=wv*f.w;
        }
    }
    const float* np_ = nc2 + (size_t)b*DD*HW + h*WW + w;
    for (int d=0; d<DD; ++d) {
        float4 f = *(const float4*)(np_ + (size_t)d*HW);
        #pragma unroll
        for (int j=0;j<8;++j) {
            float wv = rw[(o0+j)*(CC+DD) + CC + d];
            acc[j][0]+=wv*f.x; acc[j][1]+=wv*f.y; acc[j][2]+=wv*f.z; acc[j][3]+=wv*f.w;
        }
    }
    #pragma unroll
    for (int j=0;j<8;++j) {
        float bias = rb[o0+j];
        float4 o; o.x=eluf(acc[j][0]+bias); o.y=eluf(acc[j][1]+bias);
                  o.z=eluf(acc[j][2]+bias); o.w=eluf(acc[j][3]+bias);
        *(float4*)(xout + ((size_t)(b*CC+o0+j))*HW + h*WW + w) = o;
    }
}

extern "C" void kernel_launch(void* const* d_in, const int* in_sizes, int n_in,
                              void* d_out, int out_size, void* d_ws, size_t ws_size,
                              hipStream_t stream)
{
    const float* t_feat = (const float*)d_in[0];
    const float* s_feat = (const float*)d_in[1];
    const float* directs= (const float*)d_in[2];
    const float* qw = (const float*)d_in[3];
    const float* qb = (const float*)d_in[4];
    const float* kw = (const float*)d_in[5];
    const float* kb = (const float*)d_in[6];
    const float* vw = (const float*)d_in[7];
    const float* vb = (const float*)d_in[8];
    const float* p1w= (const float*)d_in[9];
    const float* p1b= (const float*)d_in[10];
    const float* p2w= (const float*)d_in[11];
    const float* p2b= (const float*)d_in[12];
    const float* rw = (const float*)d_in[13];
    const float* rb = (const float*)d_in[14];
    const int* img_w= (const int*)d_in[15];

    float* ws    = (float*)d_ws;
    float* qbuf  = ws;                   // B*64*HW
    float* kbuf  = qbuf  + 1572864;
    float* vbuf  = kbuf  + 1572864;
    float* aggv  = vbuf  + 1572864;
    float* cost1 = aggv  + 1572864;      // B*32*HW
    float* h1    = cost1 + 786432;
    float* nc2   = h1    + 1572864;
    size_t need_bytes = (size_t)(1572864*4 + 786432*2 + 1572864) * sizeof(float);
    if (ws_size < need_bytes) return;

    float* xout     = (float*)d_out;                  // [B,256,H,W]
    float* cost_out = xout + (size_t)BB*CC*HW;        // [B,32,H,W]

    k_qkv  <<<576, 256, 0, stream>>>(t_feat, s_feat, qw,qb,kw,kb,vw,vb, qbuf,kbuf,vbuf);
    k_cost <<<128, 192, 0, stream>>>(qbuf, kbuf, directs, img_w, cost1);
    k_agg  <<<128, 192, 0, stream>>>(vbuf, cost1, directs, img_w, aggv);
    k_conv1<<<192, 256, 0, stream>>>(qbuf, aggv, p1w, p1b, h1);
    k_conv2<<<96,  256, 0, stream>>>(h1, p2w, p2b, cost1, cost_out);
    k_sm2  <<<96,  256, 0, stream>>>(cost_out, nc2);
    k_final<<<768, 256, 0, stream>>>(t_feat, nc2, rw, rb, xout);
}

// Round 3
// 311.192 us; speedup vs baseline: 2.6699x; 1.6256x over previous
//
#include <hip/hip_runtime.h>

#define BB 2
#define CC 256
#define CQ 64
#define DD 32
#define HH 64
#define WW 192
#define HW (HH*WW)     // 12288
#define NPIX (BB*HW)   // 24576

typedef __attribute__((ext_vector_type(8))) short bf16x8;
typedef __attribute__((ext_vector_type(4))) float f32x4;

__device__ __forceinline__ float b2f(ushort s){ return __uint_as_float(((uint)s)<<16); }
__device__ __forceinline__ ushort f2b(float f){
    uint u = __float_as_uint(f);
    return (ushort)((u + 0x7fffu + ((u>>16)&1u)) >> 16);
}
__device__ __forceinline__ float eluf(float v){ return v > 0.f ? v : (__expf(v)-1.f); }

// ---------- prep: f32 NCHW -> bf16 pixel-major [B*HW][256] ----------
__global__ __launch_bounds__(256) void k_prep_feat(
    const float* __restrict__ t_feat, const float* __restrict__ s_feat,
    ushort* __restrict__ Tt, ushort* __restrict__ Ts)
{
    int n = blockIdx.x*256 + threadIdx.x;   // B*HW*32
    int p  = n % HW;
    int r  = n / HW;
    int c8 = r % 32;
    int b  = r / 32;
    const float* tp = t_feat + ((size_t)(b*CC + c8*8))*HW + p;
    const float* sp = s_feat + ((size_t)(b*CC + c8*8))*HW + p;
    uint tu[4], su[4];
    #pragma unroll
    for (int j2=0;j2<4;++j2){
        tu[j2] = (uint)f2b(tp[(size_t)(2*j2)*HW])   | ((uint)f2b(tp[(size_t)(2*j2+1)*HW])<<16);
        su[j2] = (uint)f2b(sp[(size_t)(2*j2)*HW])   | ((uint)f2b(sp[(size_t)(2*j2+1)*HW])<<16);
    }
    size_t dst = ((size_t)(b*HW + p))*CC + c8*8;
    uint4 t4; t4.x=tu[0]; t4.y=tu[1]; t4.z=tu[2]; t4.w=tu[3];
    uint4 s4; s4.x=su[0]; s4.y=su[1]; s4.z=su[2]; s4.w=su[3];
    *(uint4*)(Tt + dst) = t4;
    *(uint4*)(Ts + dst) = s4;
}

// ---------- prep: weights -> bf16 GEMM-A layouts ----------
__global__ __launch_bounds__(256) void k_prep_w(
    const float* __restrict__ qw, const float* __restrict__ qb,
    const float* __restrict__ kw, const float* __restrict__ kb,
    const float* __restrict__ vw, const float* __restrict__ vb,
    const float* __restrict__ p1w, const float* __restrict__ p2w,
    const float* __restrict__ rw,
    ushort* __restrict__ Wqkv, float* __restrict__ bqkv,
    ushort* __restrict__ A1, ushort* __restrict__ A2, ushort* __restrict__ Ar)
{
    int id = blockIdx.x*256 + threadIdx.x;
    if (id < 49152) {                      // Wqkv [192][256]
        int o = id / 256, c = id % 256;
        float v = (o<64)? qw[o*256+c] : (o<128)? kw[(o-64)*256+c] : vw[(o-128)*256+c];
        Wqkv[id] = f2b(v);
    } else if (id < 49344) {               // bqkv [192]
        int o = id - 49152;
        bqkv[o] = (o<64)? qb[o] : (o<128)? kb[o-64] : vb[o-128];
    } else if (id < 49344+73728) {         // A1 [64][9*128], k = t*128+ci
        int i = id - 49344;
        int o = i/1152, r = i%1152, t = r/128, ci = r%128;
        A1[i] = f2b(p1w[(size_t)(o*128+ci)*9 + t]);
    } else if (id < 49344+73728+18432) {   // A2 [32][9*64]
        int i = id - (49344+73728);
        int o = i/576, r = i%576, t = r/64, ci = r%64;
        A2[i] = f2b(p2w[(size_t)(o*64+ci)*9 + t]);
    } else if (id < 49344+73728+18432+73728) {  // Ar [256][288]
        int i = id - (49344+73728+18432);
        Ar[i] = f2b(rw[i]);
    }
}

// ---------- G1: qkv conv1x1 as MFMA GEMM ----------
// grid = 3(g) * 384(n64); block 4 waves = 4 m-tiles of the 64-row group
__global__ __launch_bounds__(256) void g_qkv(
    const ushort* __restrict__ Tt, const ushort* __restrict__ Ts,
    const ushort* __restrict__ Wqkv, const float* __restrict__ bqkv,
    ushort* __restrict__ X1, ushort* __restrict__ Vb)
{
    int wv = threadIdx.x >> 6;
    int lane = threadIdx.x & 63;
    int lm = lane & 15, lk = lane >> 4;
    int g  = blockIdx.x / 384;
    int n0 = (blockIdx.x % 384) * 64;
    const ushort* Bsrc = (g==0) ? Tt : Ts;
    const ushort* Ap = Wqkv + (size_t)(g*64 + wv*16 + lm)*CC + lk*8;
    const ushort* Bp = Bsrc + (size_t)n0*CC + lk*8;
    f32x4 acc[4];
    #pragma unroll
    for (int i=0;i<4;++i) acc[i] = (f32x4){0.f,0.f,0.f,0.f};
    for (int k0=0; k0<CC; k0+=32){
        bf16x8 a = *(const bf16x8*)(Ap + k0);
        #pragma unroll
        for (int nt=0; nt<4; ++nt){
            bf16x8 bb = *(const bf16x8*)(Bp + (size_t)(nt*16+lm)*CC + k0);
            acc[nt] = __builtin_amdgcn_mfma_f32_16x16x32_bf16(a, bb, acc[nt], 0,0,0);
        }
    }
    int ob = g*64 + wv*16 + lk*4;   // bias index base
    int ol = wv*16 + lk*4;          // channel within 64
    #pragma unroll
    for (int nt=0; nt<4; ++nt){
        int p = n0 + nt*16 + lm;
        uint u0 = (uint)f2b(acc[nt][0]+bqkv[ob])   | ((uint)f2b(acc[nt][1]+bqkv[ob+1])<<16);
        uint u1 = (uint)f2b(acc[nt][2]+bqkv[ob+2]) | ((uint)f2b(acc[nt][3]+bqkv[ob+3])<<16);
        ushort* dst;
        if (g==0)      dst = X1 + (size_t)p*128 + ol;        // q half
        else if (g==1) dst = X1 + (size_t)p*128 + 64 + ol;   // K staged into X1 agg-half (overwritten later)
        else           dst = Vb + (size_t)p*64 + ol;
        *(uint2*)dst = make_uint2(u0, u1);
    }
}

// ---------- k_ca: cost + softmax + aggV (merged) ----------
// block = (b,h); K/V rows staged in LDS with XOR swizzle
__global__ __launch_bounds__(192) void k_ca(
    ushort* __restrict__ X1, const ushort* __restrict__ Vb,
    const float* __restrict__ directs, const int* __restrict__ img_w_p,
    float* __restrict__ C1)
{
    __shared__ ushort sK[192*64];
    __shared__ ushort sV[192*64];
    int bh = blockIdx.x; int b = bh / HH; int h = bh % HH;
    size_t rowbase = (size_t)b*HW + (size_t)h*WW;
    for (int ic = threadIdx.x; ic < 192*8; ic += 192){
        int x = ic >> 3, c8 = ic & 7;
        int sw = (x*64 + c8*8) ^ ((x&7)<<3);
        *(uint4*)&sK[sw] = *(const uint4*)(X1 + (rowbase + x)*128 + 64 + c8*8);
        *(uint4*)&sV[sw] = *(const uint4*)(Vb + (rowbase + x)*64 + c8*8);
    }
    __syncthreads();
    int w = threadIdx.x;
    size_t n = rowbase + w;
    float qf[64];
    #pragma unroll
    for (int c8=0;c8<8;++c8){
        bf16x8 qv = *(const bf16x8*)(X1 + n*128 + c8*8);
        #pragma unroll
        for (int j=0;j<8;++j) qf[c8*8+j] = b2f((ushort)qv[j]);
    }
    int imw = img_w_p[0];
    float rel = (imw != 640) ? (640.0f/(float)imw) : 1.0f;
    float sf = 0.01f * rel * directs[b] * (float)(WW-1);

    float cost[DD];
    #pragma unroll
    for (int d=0; d<DD; ++d){
        float srcx = fminf(fmaxf((float)w + (float)d*sf, 0.f), 191.0f);
        int x0 = (int)floorf(srcx);
        int x1 = min(x0+1, 191);
        float fr = srcx - (float)x0;
        float acc = 0.f;
        #pragma unroll
        for (int c8=0;c8<8;++c8){
            bf16x8 k0v = *(const bf16x8*)&sK[(x0*64 + c8*8) ^ ((x0&7)<<3)];
            bf16x8 k1v = *(const bf16x8*)&sK[(x1*64 + c8*8) ^ ((x1&7)<<3)];
            #pragma unroll
            for (int j=0;j<8;++j){
                float g0=b2f((ushort)k0v[j]), g1=b2f((ushort)k1v[j]);
                acc += qf[c8*8+j] * (g0 + fr*(g1-g0));
            }
        }
        cost[d] = acc * 0.125f;
    }
    float* cp = C1 + n*DD;
    #pragma unroll
    for (int d=0; d<DD; d+=4){
        f32x4 t; t[0]=cost[d]; t[1]=cost[d+1]; t[2]=cost[d+2]; t[3]=cost[d+3];
        *(f32x4*)(cp + d) = t;
    }
    float m = cost[0];
    #pragma unroll
    for (int d=1; d<DD; ++d) m = fmaxf(m, cost[d]);
    float s = 0.f;
    #pragma unroll
    for (int d=0; d<DD; ++d){ cost[d] = __expf(cost[d]-m); s += cost[d]; }
    float inv = 1.f/s;
    float agg[64];
    #pragma unroll
    for (int c=0;c<64;++c) agg[c]=0.f;
    #pragma unroll
    for (int d=0; d<DD; ++d){
        float pd = cost[d]*inv;
        float srcx = fminf(fmaxf((float)w + (float)d*sf, 0.f), 191.0f);
        int x0 = (int)floorf(srcx);
        int x1 = min(x0+1, 191);
        float fr = srcx - (float)x0;
        #pragma unroll
        for (int c8=0;c8<8;++c8){
            bf16x8 v0v = *(const bf16x8*)&sV[(x0*64 + c8*8) ^ ((x0&7)<<3)];
            bf16x8 v1v = *(const bf16x8*)&sV[(x1*64 + c8*8) ^ ((x1&7)<<3)];
            #pragma unroll
            for (int j=0;j<8;++j){
                float g0=b2f((ushort)v0v[j]), g1=b2f((ushort)v1v[j]);
                agg[c8*8+j] += pd*(g0 + fr*(g1-g0));
            }
        }
    }
    ushort* op = X1 + n*128 + 64;   // overwrite K-half with agg (staging done)
    #pragma unroll
    for (int c8=0;c8<8;++c8){
        uint u[4];
        #pragma unroll
        for (int j2=0;j2<4;++j2)
            u[j2] = (uint)f2b(agg[c8*8+j2*2]) | ((uint)f2b(agg[c8*8+j2*2+1])<<16);
        uint4 q4; q4.x=u[0]; q4.y=u[1]; q4.z=u[2]; q4.w=u[3];
        *(uint4*)(op + c8*8) = q4;
    }
}

// ---------- G2: conv3x3 p1 as implicit GEMM, ELU ----------
// grid = 768 (n32 tiles); block 4 waves = m-tiles 0..3 (M=64)
__global__ __launch_bounds__(256) void g_conv1(
    const ushort* __restrict__ X1, const ushort* __restrict__ A1,
    const float* __restrict__ p1b, ushort* __restrict__ X2)
{
    int wv = threadIdx.x >> 6;
    int lane = threadIdx.x & 63;
    int lm = lane & 15, lk = lane >> 4;
    int n0 = blockIdx.x * 32;
    int b  = n0 / HW;
    const ushort* Ap = A1 + (size_t)(wv*16 + lm)*1152 + lk*8;
    f32x4 acc[2];
    acc[0] = (f32x4){0.f,0.f,0.f,0.f}; acc[1] = (f32x4){0.f,0.f,0.f,0.f};
    int hh[2], wx[2];
    #pragma unroll
    for (int nt=0;nt<2;++nt){
        int p = (n0 % HW) + nt*16 + lm;
        hh[nt] = p / WW; wx[nt] = p % WW;
    }
    for (int t=0; t<9; ++t){
        int dh = t/3 - 1, dw = t%3 - 1;
        const ushort* bp[2]; bool val[2];
        #pragma unroll
        for (int nt=0;nt<2;++nt){
            int hs = hh[nt] + dh, wsx = wx[nt] + dw;
            val[nt] = (hs>=0 && hs<HH && wsx>=0 && wsx<WW);
            bp[nt] = X1 + ((size_t)b*HW + (size_t)hs*WW + wsx)*128 + lk*8;
        }
        const ushort* At = Ap + t*128;
        #pragma unroll
        for (int c0=0; c0<128; c0+=32){
            bf16x8 a = *(const bf16x8*)(At + c0);
            #pragma unroll
            for (int nt=0;nt<2;++nt){
                bf16x8 bb = {0,0,0,0,0,0,0,0};
                if (val[nt]) bb = *(const bf16x8*)(bp[nt] + c0);
                acc[nt] = __builtin_amdgcn_mfma_f32_16x16x32_bf16(a, bb, acc[nt], 0,0,0);
            }
        }
    }
    int o = wv*16 + lk*4;
    #pragma unroll
    for (int nt=0; nt<2; ++nt){
        int pg = n0 + nt*16 + lm;
        uint u0 = (uint)f2b(eluf(acc[nt][0]+p1b[o]))   | ((uint)f2b(eluf(acc[nt][1]+p1b[o+1]))<<16);
        uint u1 = (uint)f2b(eluf(acc[nt][2]+p1b[o+2])) | ((uint)f2b(eluf(acc[nt][3]+p1b[o+3]))<<16);
        *(uint2*)(X2 + (size_t)pg*64 + o) = make_uint2(u0, u1);
    }
}

// ---------- G3: conv3x3 p2 + residual avg -> cost_out ----------
// grid = 768; block 2 waves = m-tiles 0..1 (M=32)
__global__ __launch_bounds__(128) void g_conv2(
    const ushort* __restrict__ X2, const ushort* __restrict__ A2,
    const float* __restrict__ p2b, const float* __restrict__ C1,
    float* __restrict__ cost_out)
{
    int wv = threadIdx.x >> 6;
    int lane = threadIdx.x & 63;
    int lm = lane & 15, lk = lane >> 4;
    int n0 = blockIdx.x * 32;
    int b  = n0 / HW;
    const ushort* Ap = A2 + (size_t)(wv*16 + lm)*576 + lk*8;
    f32x4 acc[2];
    acc[0] = (f32x4){0.f,0.f,0.f,0.f}; acc[1] = (f32x4){0.f,0.f,0.f,0.f};
    int hh[2], wx[2];
    #pragma unroll
    for (int nt=0;nt<2;++nt){
        int p = (n0 % HW) + nt*16 + lm;
        hh[nt] = p / WW; wx[nt] = p % WW;
    }
    for (int t=0; t<9; ++t){
        int dh = t/3 - 1, dw = t%3 - 1;
        const ushort* bp[2]; bool val[2];
        #pragma unroll
        for (int nt=0;nt<2;++nt){
            int hs = hh[nt] + dh, wsx = wx[nt] + dw;
            val[nt] = (hs>=0 && hs<HH && wsx>=0 && wsx<WW);
            bp[nt] = X2 + ((size_t)b*HW + (size_t)hs*WW + wsx)*64 + lk*8;
        }
        const ushort* At = Ap + t*64;
        #pragma unroll
        for (int c0=0; c0<64; c0+=32){
            bf16x8 a = *(const bf16x8*)(At + c0);
            #pragma unroll
            for (int nt=0;nt<2;++nt){
                bf16x8 bb = {0,0,0,0,0,0,0,0};
                if (val[nt]) bb = *(const bf16x8*)(bp[nt] + c0);
                acc[nt] = __builtin_amdgcn_mfma_f32_16x16x32_bf16(a, bb, acc[nt], 0,0,0);
            }
        }
    }
    int o = wv*16 + lk*4;   // d index base
    #pragma unroll
    for (int nt=0; nt<2; ++nt){
        int pg = n0 + nt*16 + lm;
        int pl = pg - b*HW;
        f32x4 cv = *(const f32x4*)(C1 + (size_t)pg*DD + o);
        #pragma unroll
        for (int j=0;j<4;++j){
            float out = (cv[j] + acc[nt][j] + p2b[o+j]) * 0.5f;
            cost_out[((size_t)(b*DD + o + j))*HW + pl] = out;
        }
    }
}

// ---------- softmax over D -> NC (bf16 pixel-major) ----------
__global__ __launch_bounds__(256) void k_sm2(
    const float* __restrict__ cost_out, ushort* __restrict__ NC)
{
    int n = blockIdx.x*256 + threadIdx.x;   // 24576
    int b = n / HW, pl = n % HW;
    const float* cp = cost_out + (size_t)b*DD*HW + pl;
    float v[DD]; float m = -1e30f;
    #pragma unroll
    for (int d=0; d<DD; ++d){ v[d] = cp[(size_t)d*HW]; m = fmaxf(m, v[d]); }
    float s = 0.f;
    #pragma unroll
    for (int d=0; d<DD; ++d){ v[d] = __expf(v[d]-m); s += v[d]; }
    float inv = 1.f/s;
    ushort* op = NC + (size_t)n*DD;
    #pragma unroll
    for (int d8=0; d8<4; ++d8){
        uint u[4];
        #pragma unroll
        for (int j2=0;j2<4;++j2)
            u[j2] = (uint)f2b(v[d8*8+j2*2]*inv) | ((uint)f2b(v[d8*8+j2*2+1]*inv)<<16);
        uint4 q4; q4.x=u[0]; q4.y=u[1]; q4.z=u[2]; q4.w=u[3];
        *(uint4*)(op + d8*8) = q4;
    }
}

// ---------- G4: final conv1x1 on concat(t_feat, nc2), ELU ----------
// grid = 4(mg) * 384(n64); block 4 waves m-stacked
__global__ __launch_bounds__(256) void g_final(
    const ushort* __restrict__ Tt, const ushort* __restrict__ NC,
    const ushort* __restrict__ Ar, const float* __restrict__ rb,
    float* __restrict__ xout)
{
    int wv = threadIdx.x >> 6;
    int lane = threadIdx.x & 63;
    int lm = lane & 15, lk = lane >> 4;
    int mg = blockIdx.x / 384;
    int n0 = (blockIdx.x % 384) * 64;
    const ushort* Ap = Ar + (size_t)(mg*64 + wv*16 + lm)*288 + lk*8;
    f32x4 acc[4];
    #pragma unroll
    for (int i=0;i<4;++i) acc[i] = (f32x4){0.f,0.f,0.f,0.f};
    for (int k0=0; k0<288; k0+=32){
        bf16x8 a = *(const bf16x8*)(Ap + k0);
        #pragma unroll
        for (int nt=0; nt<4; ++nt){
            int p = n0 + nt*16 + lm;
            const ushort* src = (k0 < 256) ? (Tt + (size_t)p*CC + k0 + lk*8)
                                           : (NC + (size_t)p*DD + lk*8);
            bf16x8 bb = *(const bf16x8*)src;
            acc[nt] = __builtin_amdgcn_mfma_f32_16x16x32_bf16(a, bb, acc[nt], 0,0,0);
        }
    }
    int o = mg*64 + wv*16 + lk*4;
    #pragma unroll
    for (int nt=0; nt<4; ++nt){
        int p = n0 + nt*16 + lm;
        int b = p / HW, pl = p % HW;
        #pragma unroll
        for (int j=0;j<4;++j)
            xout[((size_t)(b*CC + o + j))*HW + pl] = eluf(acc[nt][j] + rb[o+j]);
    }
}

extern "C" void kernel_launch(void* const* d_in, const int* in_sizes, int n_in,
                              void* d_out, int out_size, void* d_ws, size_t ws_size,
                              hipStream_t stream)
{
    const float* t_feat = (const float*)d_in[0];
    const float* s_feat = (const float*)d_in[1];
    const float* directs= (const float*)d_in[2];
    const float* qw = (const float*)d_in[3];
    const float* qb = (const float*)d_in[4];
    const float* kw = (const float*)d_in[5];
    const float* kb = (const float*)d_in[6];
    const float* vw = (const float*)d_in[7];
    const float* vb = (const float*)d_in[8];
    const float* p1w= (const float*)d_in[9];
    const float* p1b= (const float*)d_in[10];
    const float* p2w= (const float*)d_in[11];
    const float* p2b= (const float*)d_in[12];
    const float* rw = (const float*)d_in[13];
    const float* rb = (const float*)d_in[14];
    const int* img_w= (const int*)d_in[15];

    // workspace layout (byte offsets, lifetime-aliased)
    char* wsb = (char*)d_ws;
    ushort* Tt   = (ushort*)(wsb + 0);           // 12,582,912 B  [NPIX][256] bf16
    char*  tsreg = wsb + 12582912;               // 12,582,912 B region
    ushort* Ts   = (ushort*)tsreg;               //   Ts (dead after g_qkv)
    ushort* X2   = (ushort*)tsreg;               //   X2 [NPIX][64] bf16 (3,145,728) aliases Ts
    float*  C1   = (float*)(tsreg + 3145728);    //   C1 [NPIX][32] f32 (3,145,728) aliases Ts
    ushort* X1   = (ushort*)(wsb + 25165824);    // 6,291,456 B [NPIX][128] bf16 (q | K->agg)
    ushort* Vb   = (ushort*)(wsb + 31457280);    // 3,145,728 B [NPIX][64] bf16
    ushort* NC   = (ushort*)(wsb + 31457280);    // aliases Vb after k_ca
    ushort* Wqkv = (ushort*)(wsb + 34603008);    // 98,304 B
    float*  bqkv = (float*) (wsb + 34701312);    // 768 B (pad to 1024)
    ushort* A1   = (ushort*)(wsb + 34702336);    // 147,456 B
    ushort* A2   = (ushort*)(wsb + 34849792);    // 36,864 B
    ushort* Ar   = (ushort*)(wsb + 34886656);    // 147,456 B -> end 35,034,112
    if (ws_size < 35034112) return;

    float* xout     = (float*)d_out;                 // [B,256,H,W] f32
    float* cost_out = xout + (size_t)BB*CC*HW;       // [B,32,H,W] f32

    k_prep_feat<<<3072, 256, 0, stream>>>(t_feat, s_feat, Tt, Ts);
    k_prep_w  <<<841,  256, 0, stream>>>(qw,qb,kw,kb,vw,vb,p1w,p2w,rw, Wqkv,bqkv,A1,A2,Ar);
    g_qkv     <<<1152, 256, 0, stream>>>(Tt, Ts, Wqkv, bqkv, X1, Vb);
    k_ca      <<<128,  192, 0, stream>>>(X1, Vb, directs, img_w, C1);
    g_conv1   <<<768,  256, 0, stream>>>(X1, A1, p1b, X2);
    g_conv2   <<<768,  128, 0, stream>>>(X2, A2, p2b, C1, cost_out);
    k_sm2     <<<96,   256, 0, stream>>>(cost_out, NC);
    g_final   <<<1536, 256, 0, stream>>>(Tt, NC, Ar, rb, xout);
}

// Round 4
// 152.952 us; speedup vs baseline: 5.4322x; 2.0346x over previous
//
#include <hip/hip_runtime.h>

#define BB 2
#define CC 256
#define CQ 64
#define DD 32
#define HH 64
#define WW 192
#define HW (HH*WW)     // 12288
#define NPIX (BB*HW)   // 24576

typedef __attribute__((ext_vector_type(8))) short bf16x8;
typedef __attribute__((ext_vector_type(4))) float f32x4;

__device__ __forceinline__ float b2f(ushort s){ return __uint_as_float(((uint)s)<<16); }
__device__ __forceinline__ ushort f2b(float f){
    uint u = __float_as_uint(f);
    return (ushort)((u + 0x7fffu + ((u>>16)&1u)) >> 16);
}
__device__ __forceinline__ float eluf(float v){ return v > 0.f ? v : (__expf(v)-1.f); }

// ---------- prep: f32 NCHW -> bf16 pixel-major [B*HW][256] ----------
__global__ __launch_bounds__(256) void k_prep_feat(
    const float* __restrict__ t_feat, const float* __restrict__ s_feat,
    ushort* __restrict__ Tt, ushort* __restrict__ Ts)
{
    int n = blockIdx.x*256 + threadIdx.x;   // B*HW*32
    int p  = n % HW;
    int r  = n / HW;
    int c8 = r % 32;
    int b  = r / 32;
    const float* tp = t_feat + ((size_t)(b*CC + c8*8))*HW + p;
    const float* sp = s_feat + ((size_t)(b*CC + c8*8))*HW + p;
    uint tu[4], su[4];
    #pragma unroll
    for (int j2=0;j2<4;++j2){
        tu[j2] = (uint)f2b(tp[(size_t)(2*j2)*HW])   | ((uint)f2b(tp[(size_t)(2*j2+1)*HW])<<16);
        su[j2] = (uint)f2b(sp[(size_t)(2*j2)*HW])   | ((uint)f2b(sp[(size_t)(2*j2+1)*HW])<<16);
    }
    size_t dst = ((size_t)(b*HW + p))*CC + c8*8;
    uint4 t4; t4.x=tu[0]; t4.y=tu[1]; t4.z=tu[2]; t4.w=tu[3];
    uint4 s4; s4.x=su[0]; s4.y=su[1]; s4.z=su[2]; s4.w=su[3];
    *(uint4*)(Tt + dst) = t4;
    *(uint4*)(Ts + dst) = s4;
}

// ---------- prep: weights -> bf16 GEMM-A layouts ----------
__global__ __launch_bounds__(256) void k_prep_w(
    const float* __restrict__ qw, const float* __restrict__ qb,
    const float* __restrict__ kw, const float* __restrict__ kb,
    const float* __restrict__ vw, const float* __restrict__ vb,
    const float* __restrict__ p1w, const float* __restrict__ p2w,
    const float* __restrict__ rw,
    ushort* __restrict__ Wqkv, float* __restrict__ bqkv,
    ushort* __restrict__ A1, ushort* __restrict__ A2, ushort* __restrict__ Ar)
{
    int id = blockIdx.x*256 + threadIdx.x;
    if (id < 49152) {                      // Wqkv [192][256]
        int o = id / 256, c = id % 256;
        float v = (o<64)? qw[o*256+c] : (o<128)? kw[(o-64)*256+c] : vw[(o-128)*256+c];
        Wqkv[id] = f2b(v);
    } else if (id < 49344) {               // bqkv [192]
        int o = id - 49152;
        bqkv[o] = (o<64)? qb[o] : (o<128)? kb[o-64] : vb[o-128];
    } else if (id < 49344+73728) {         // A1 [64][9*128], k = t*128+ci
        int i = id - 49344;
        int o = i/1152, r = i%1152, t = r/128, ci = r%128;
        A1[i] = f2b(p1w[(size_t)(o*128+ci)*9 + t]);
    } else if (id < 49344+73728+18432) {   // A2 [32][9*64]
        int i = id - (49344+73728);
        int o = i/576, r = i%576, t = r/64, ci = r%64;
        A2[i] = f2b(p2w[(size_t)(o*64+ci)*9 + t]);
    } else if (id < 49344+73728+18432+73728) {  // Ar [256][288]
        int i = id - (49344+73728+18432);
        Ar[i] = f2b(rw[i]);
    }
}

// ---------- G1: qkv conv1x1 as MFMA GEMM ----------
__global__ __launch_bounds__(256) void g_qkv(
    const ushort* __restrict__ Tt, const ushort* __restrict__ Ts,
    const ushort* __restrict__ Wqkv, const float* __restrict__ bqkv,
    ushort* __restrict__ X1, ushort* __restrict__ Vb)
{
    int wv = threadIdx.x >> 6;
    int lane = threadIdx.x & 63;
    int lm = lane & 15, lk = lane >> 4;
    int g  = blockIdx.x / 384;
    int n0 = (blockIdx.x % 384) * 64;
    const ushort* Bsrc = (g==0) ? Tt : Ts;
    const ushort* Ap = Wqkv + (size_t)(g*64 + wv*16 + lm)*CC + lk*8;
    const ushort* Bp = Bsrc + (size_t)n0*CC + lk*8;
    f32x4 acc[4];
    #pragma unroll
    for (int i=0;i<4;++i) acc[i] = (f32x4){0.f,0.f,0.f,0.f};
    for (int k0=0; k0<CC; k0+=32){
        bf16x8 a = *(const bf16x8*)(Ap + k0);
        #pragma unroll
        for (int nt=0; nt<4; ++nt){
            bf16x8 bb = *(const bf16x8*)(Bp + (size_t)(nt*16+lm)*CC + k0);
            acc[nt] = __builtin_amdgcn_mfma_f32_16x16x32_bf16(a, bb, acc[nt], 0,0,0);
        }
    }
    int ob = g*64 + wv*16 + lk*4;   // bias index base
    int ol = wv*16 + lk*4;          // channel within 64
    #pragma unroll
    for (int nt=0; nt<4; ++nt){
        int p = n0 + nt*16 + lm;
        uint u0 = (uint)f2b(acc[nt][0]+bqkv[ob])   | ((uint)f2b(acc[nt][1]+bqkv[ob+1])<<16);
        uint u1 = (uint)f2b(acc[nt][2]+bqkv[ob+2]) | ((uint)f2b(acc[nt][3]+bqkv[ob+3])<<16);
        ushort* dst;
        if (g==0)      dst = X1 + (size_t)p*128 + ol;        // q half
        else if (g==1) dst = X1 + (size_t)p*128 + 64 + ol;   // K half (persistent)
        else           dst = Vb + (size_t)p*64 + ol;
        *(uint2*)dst = make_uint2(u0, u1);
    }
}

// ---------- k_ca: cost + softmax + aggV, phase-split, 2 blocks/row ----------
// block = (b, h, half); 768 threads; K/V full row + Q half-row staged in LDS
__global__ __launch_bounds__(768) void k_ca(
    const ushort* __restrict__ X1, const ushort* __restrict__ Vb,
    const float* __restrict__ directs, const int* __restrict__ img_w_p,
    float* __restrict__ C1, ushort* __restrict__ Agg)
{
    __shared__ ushort sK[192*64];   // 24 KiB, XOR-swizzled
    __shared__ ushort sV[192*64];   // 24 KiB
    __shared__ ushort sQ[96*64];    // 12 KiB
    __shared__ float  sC[32*96];    // 12 KiB  [d][wl]
    int blk = blockIdx.x;
    int b    = blk >> 7;
    int rem  = blk & 127;
    int h    = rem >> 1;
    int half = rem & 1;
    int w0   = half * 96;
    size_t rowbase = (size_t)b*HW + (size_t)h*WW;
    int tid = threadIdx.x;

    for (int i = tid; i < 1536; i += 768){       // full K/V row
        int x = i >> 3, c8 = i & 7;
        int sw = (x*64 + c8*8) ^ ((x&7)<<3);
        *(uint4*)&sK[sw] = *(const uint4*)(X1 + (rowbase + x)*128 + 64 + c8*8);
        *(uint4*)&sV[sw] = *(const uint4*)(Vb + (rowbase + x)*64 + c8*8);
    }
    {
        int x = tid >> 3, c8 = tid & 7;          // Q half-row (768 slots)
        int sw = (x*64 + c8*8) ^ ((x&7)<<3);
        *(uint4*)&sQ[sw] = *(const uint4*)(X1 + (rowbase + w0 + x)*128 + c8*8);
    }
    __syncthreads();

    int imw = img_w_p[0];
    float rel = (imw != 640) ? (640.0f/(float)imw) : 1.0f;
    float sf = 0.01f * rel * directs[b] * 191.0f;

    // ---- phase A: cost ----
    {
        int wl = tid % 96;
        int dq = tid / 96;           // 0..7, 4 d's each
        int w  = w0 + wl;
        float qf[64];
        #pragma unroll
        for (int c8=0;c8<8;++c8){
            bf16x8 qv = *(const bf16x8*)&sQ[(wl*64 + c8*8) ^ ((wl&7)<<3)];
            #pragma unroll
            for (int j=0;j<8;++j) qf[c8*8+j] = b2f((ushort)qv[j]);
        }
        #pragma unroll
        for (int j=0;j<4;++j){
            int d = dq*4 + j;
            float srcx = fminf(fmaxf((float)w + (float)d*sf, 0.f), 191.0f);
            int x0 = (int)floorf(srcx);
            int x1 = min(x0+1, 191);
            float fr = srcx - (float)x0;
            float acc = 0.f;
            #pragma unroll
            for (int c8=0;c8<8;++c8){
                bf16x8 k0v = *(const bf16x8*)&sK[(x0*64 + c8*8) ^ ((x0&7)<<3)];
                bf16x8 k1v = *(const bf16x8*)&sK[(x1*64 + c8*8) ^ ((x1&7)<<3)];
                #pragma unroll
                for (int jj=0;jj<8;++jj){
                    float g0=b2f((ushort)k0v[jj]), g1=b2f((ushort)k1v[jj]);
                    acc += qf[c8*8+jj] * (g0 + fr*(g1-g0));
                }
            }
            sC[d*96 + wl] = acc * 0.125f;
        }
    }
    __syncthreads();

    // ---- phase B: softmax over d + coalesced C1 write ----
    if (tid < 96){
        int w = w0 + tid;
        float v[DD]; float m = -1e30f;
        #pragma unroll
        for (int d=0; d<DD; ++d){ v[d] = sC[d*96 + tid]; m = fmaxf(m, v[d]); }
        float* cp = C1 + (rowbase + w)*DD;
        #pragma unroll
        for (int d=0; d<DD; d+=4){
            f32x4 t; t[0]=v[d]; t[1]=v[d+1]; t[2]=v[d+2]; t[3]=v[d+3];
            *(f32x4*)(cp + d) = t;
        }
        float s = 0.f;
        #pragma unroll
        for (int d=0; d<DD; ++d){ v[d] = __expf(v[d]-m); s += v[d]; }
        float inv = 1.f/s;
        #pragma unroll
        for (int d=0; d<DD; ++d) sC[d*96 + tid] = v[d]*inv;
    }
    __syncthreads();

    // ---- phase C: agg_v ----
    {
        int wl = tid % 96;
        int cg = tid / 96;           // 0..7, 8 channels each
        int w  = w0 + wl;
        float agg[8];
        #pragma unroll
        for (int j=0;j<8;++j) agg[j]=0.f;
        for (int d=0; d<DD; ++d){
            float pd = sC[d*96 + wl];
            float srcx = fminf(fmaxf((float)w + (float)d*sf, 0.f), 191.0f);
            int x0 = (int)floorf(srcx);
            int x1 = min(x0+1, 191);
            float fr = srcx - (float)x0;
            bf16x8 v0v = *(const bf16x8*)&sV[(x0*64 + cg*8) ^ ((x0&7)<<3)];
            bf16x8 v1v = *(const bf16x8*)&sV[(x1*64 + cg*8) ^ ((x1&7)<<3)];
            #pragma unroll
            for (int j=0;j<8;++j){
                float g0=b2f((ushort)v0v[j]), g1=b2f((ushort)v1v[j]);
                agg[j] += pd*(g0 + fr*(g1-g0));
            }
        }
        uint u[4];
        #pragma unroll
        for (int j2=0;j2<4;++j2)
            u[j2] = (uint)f2b(agg[j2*2]) | ((uint)f2b(agg[j2*2+1])<<16);
        uint4 q4; q4.x=u[0]; q4.y=u[1]; q4.z=u[2]; q4.w=u[3];
        *(uint4*)(Agg + (rowbase + w)*64 + cg*8) = q4;
    }
}

// ---------- G2: conv3x3 p1 as implicit GEMM, ELU ----------
__global__ __launch_bounds__(256) void g_conv1(
    const ushort* __restrict__ X1, const ushort* __restrict__ Agg,
    const ushort* __restrict__ A1, const float* __restrict__ p1b,
    ushort* __restrict__ X2)
{
    int wv = threadIdx.x >> 6;
    int lane = threadIdx.x & 63;
    int lm = lane & 15, lk = lane >> 4;
    int n0 = blockIdx.x * 32;
    int b  = n0 / HW;
    const ushort* Ap = A1 + (size_t)(wv*16 + lm)*1152 + lk*8;
    f32x4 acc[2];
    acc[0] = (f32x4){0.f,0.f,0.f,0.f}; acc[1] = (f32x4){0.f,0.f,0.f,0.f};
    int hh[2], wx[2];
    #pragma unroll
    for (int nt=0;nt<2;++nt){
        int p = (n0 % HW) + nt*16 + lm;
        hh[nt] = p / WW; wx[nt] = p % WW;
    }
    for (int t=0; t<9; ++t){
        int dh = t/3 - 1, dw = t%3 - 1;
        const ushort* bq[2]; const ushort* ba[2]; bool val[2];
        #pragma unroll
        for (int nt=0;nt<2;++nt){
            int hs = hh[nt] + dh, wsx = wx[nt] + dw;
            val[nt] = (hs>=0 && hs<HH && wsx>=0 && wsx<WW);
            size_t pix = (size_t)b*HW + (size_t)hs*WW + wsx;
            bq[nt] = X1  + pix*128 + lk*8;
            ba[nt] = Agg + pix*64  + lk*8;
        }
        const ushort* At = Ap + t*128;
        #pragma unroll
        for (int c0=0; c0<128; c0+=32){
            bf16x8 a = *(const bf16x8*)(At + c0);
            #pragma unroll
            for (int nt=0;nt<2;++nt){
                bf16x8 bb = {0,0,0,0,0,0,0,0};
                if (val[nt]) bb = (c0 < 64) ? *(const bf16x8*)(bq[nt] + c0)
                                            : *(const bf16x8*)(ba[nt] + c0 - 64);
                acc[nt] = __builtin_amdgcn_mfma_f32_16x16x32_bf16(a, bb, acc[nt], 0,0,0);
            }
        }
    }
    int o = wv*16 + lk*4;
    #pragma unroll
    for (int nt=0; nt<2; ++nt){
        int pg = n0 + nt*16 + lm;
        uint u0 = (uint)f2b(eluf(acc[nt][0]+p1b[o]))   | ((uint)f2b(eluf(acc[nt][1]+p1b[o+1]))<<16);
        uint u1 = (uint)f2b(eluf(acc[nt][2]+p1b[o+2])) | ((uint)f2b(eluf(acc[nt][3]+p1b[o+3]))<<16);
        *(uint2*)(X2 + (size_t)pg*64 + o) = make_uint2(u0, u1);
    }
}

// ---------- G3: conv3x3 p2 + residual avg -> cost_out ----------
__global__ __launch_bounds__(128) void g_conv2(
    const ushort* __restrict__ X2, const ushort* __restrict__ A2,
    const float* __restrict__ p2b, const float* __restrict__ C1,
    float* __restrict__ cost_out)
{
    int wv = threadIdx.x >> 6;
    int lane = threadIdx.x & 63;
    int lm = lane & 15, lk = lane >> 4;
    int n0 = blockIdx.x * 32;
    int b  = n0 / HW;
    const ushort* Ap = A2 + (size_t)(wv*16 + lm)*576 + lk*8;
    f32x4 acc[2];
    acc[0] = (f32x4){0.f,0.f,0.f,0.f}; acc[1] = (f32x4){0.f,0.f,0.f,0.f};
    int hh[2], wx[2];
    #pragma unroll
    for (int nt=0;nt<2;++nt){
        int p = (n0 % HW) + nt*16 + lm;
        hh[nt] = p / WW; wx[nt] = p % WW;
    }
    for (int t=0; t<9; ++t){
        int dh = t/3 - 1, dw = t%3 - 1;
        const ushort* bp[2]; bool val[2];
        #pragma unroll
        for (int nt=0;nt<2;++nt){
            int hs = hh[nt] + dh, wsx = wx[nt] + dw;
            val[nt] = (hs>=0 && hs<HH && wsx>=0 && wsx<WW);
            bp[nt] = X2 + ((size_t)b*HW + (size_t)hs*WW + wsx)*64 + lk*8;
        }
        const ushort* At = Ap + t*64;
        #pragma unroll
        for (int c0=0; c0<64; c0+=32){
            bf16x8 a = *(const bf16x8*)(At + c0);
            #pragma unroll
            for (int nt=0;nt<2;++nt){
                bf16x8 bb = {0,0,0,0,0,0,0,0};
                if (val[nt]) bb = *(const bf16x8*)(bp[nt] + c0);
                acc[nt] = __builtin_amdgcn_mfma_f32_16x16x32_bf16(a, bb, acc[nt], 0,0,0);
            }
        }
    }
    int o = wv*16 + lk*4;   // d index base
    #pragma unroll
    for (int nt=0; nt<2; ++nt){
        int pg = n0 + nt*16 + lm;
        int pl = pg - b*HW;
        f32x4 cv = *(const f32x4*)(C1 + (size_t)pg*DD + o);
        #pragma unroll
        for (int j=0;j<4;++j){
            float out = (cv[j] + acc[nt][j] + p2b[o+j]) * 0.5f;
            cost_out[((size_t)(b*DD + o + j))*HW + pl] = out;
        }
    }
}

// ---------- softmax over D -> NC (bf16 pixel-major) ----------
__global__ __launch_bounds__(256) void k_sm2(
    const float* __restrict__ cost_out, ushort* __restrict__ NC)
{
    int n = blockIdx.x*256 + threadIdx.x;   // 24576
    int b = n / HW, pl = n % HW;
    const float* cp = cost_out + (size_t)b*DD*HW + pl;
    float v[DD]; float m = -1e30f;
    #pragma unroll
    for (int d=0; d<DD; ++d){ v[d] = cp[(size_t)d*HW]; m = fmaxf(m, v[d]); }
    float s = 0.f;
    #pragma unroll
    for (int d=0; d<DD; ++d){ v[d] = __expf(v[d]-m); s += v[d]; }
    float inv = 1.f/s;
    ushort* op = NC + (size_t)n*DD;
    #pragma unroll
    for (int d8=0; d8<4; ++d8){
        uint u[4];
        #pragma unroll
        for (int j2=0;j2<4;++j2)
            u[j2] = (uint)f2b(v[d8*8+j2*2]*inv) | ((uint)f2b(v[d8*8+j2*2+1]*inv)<<16);
        uint4 q4; q4.x=u[0]; q4.y=u[1]; q4.z=u[2]; q4.w=u[3];
        *(uint4*)(op + d8*8) = q4;
    }
}

// ---------- G4: final conv1x1 on concat(t_feat, nc2), ELU ----------
__global__ __launch_bounds__(256) void g_final(
    const ushort* __restrict__ Tt, const ushort* __restrict__ NC,
    const ushort* __restrict__ Ar, const float* __restrict__ rb,
    float* __restrict__ xout)
{
    int wv = threadIdx.x >> 6;
    int lane = threadIdx.x & 63;
    int lm = lane & 15, lk = lane >> 4;
    int mg = blockIdx.x / 384;
    int n0 = (blockIdx.x % 384) * 64;
    const ushort* Ap = Ar + (size_t)(mg*64 + wv*16 + lm)*288 + lk*8;
    f32x4 acc[4];
    #pragma unroll
    for (int i=0;i<4;++i) acc[i] = (f32x4){0.f,0.f,0.f,0.f};
    for (int k0=0; k0<288; k0+=32){
        bf16x8 a = *(const bf16x8*)(Ap + k0);
        #pragma unroll
        for (int nt=0; nt<4; ++nt){
            int p = n0 + nt*16 + lm;
            const ushort* src = (k0 < 256) ? (Tt + (size_t)p*CC + k0 + lk*8)
                                           : (NC + (size_t)p*DD + lk*8);
            bf16x8 bb = *(const bf16x8*)src;
            acc[nt] = __builtin_amdgcn_mfma_f32_16x16x32_bf16(a, bb, acc[nt], 0,0,0);
        }
    }
    int o = mg*64 + wv*16 + lk*4;
    #pragma unroll
    for (int nt=0; nt<4; ++nt){
        int p = n0 + nt*16 + lm;
        int b = p / HW, pl = p % HW;
        #pragma unroll
        for (int j=0;j<4;++j)
            xout[((size_t)(b*CC + o + j))*HW + pl] = eluf(acc[nt][j] + rb[o+j]);
    }
}

extern "C" void kernel_launch(void* const* d_in, const int* in_sizes, int n_in,
                              void* d_out, int out_size, void* d_ws, size_t ws_size,
                              hipStream_t stream)
{
    const float* t_feat = (const float*)d_in[0];
    const float* s_feat = (const float*)d_in[1];
    const float* directs= (const float*)d_in[2];
    const float* qw = (const float*)d_in[3];
    const float* qb = (const float*)d_in[4];
    const float* kw = (const float*)d_in[5];
    const float* kb = (const float*)d_in[6];
    const float* vw = (const float*)d_in[7];
    const float* vb = (const float*)d_in[8];
    const float* p1w= (const float*)d_in[9];
    const float* p1b= (const float*)d_in[10];
    const float* p2w= (const float*)d_in[11];
    const float* p2b= (const float*)d_in[12];
    const float* rw = (const float*)d_in[13];
    const float* rb = (const float*)d_in[14];
    const int* img_w= (const int*)d_in[15];

    // workspace layout (byte offsets, lifetime-aliased)
    char* wsb = (char*)d_ws;
    ushort* Tt   = (ushort*)(wsb + 0);           // 12,582,912 B  [NPIX][256] bf16
    char*  tsreg = wsb + 12582912;               // 12,582,912 B region
    ushort* Ts   = (ushort*)tsreg;               //   Ts (dead after g_qkv)
    ushort* X2   = (ushort*)tsreg;               //   X2 [NPIX][64] bf16 (3,145,728) aliases Ts
    float*  C1   = (float*)(tsreg + 3145728);    //   C1 [NPIX][32] f32 (3,145,728)
    ushort* Agg  = (ushort*)(tsreg + 6291456);   //   Agg [NPIX][64] bf16 (3,145,728)
    ushort* X1   = (ushort*)(wsb + 25165824);    // 6,291,456 B [NPIX][128] bf16 (q | K)
    ushort* Vb   = (ushort*)(wsb + 31457280);    // 3,145,728 B [NPIX][64] bf16
    ushort* NC   = (ushort*)(wsb + 31457280);    // aliases Vb after k_ca
    ushort* Wqkv = (ushort*)(wsb + 34603008);    // 98,304 B
    float*  bqkv = (float*) (wsb + 34701312);    // 768 B (pad to 1024)
    ushort* A1   = (ushort*)(wsb + 34702336);    // 147,456 B
    ushort* A2   = (ushort*)(wsb + 34849792);    // 36,864 B
    ushort* Ar   = (ushort*)(wsb + 34886656);    // 147,456 B -> end 35,034,112
    if (ws_size < 35034112) return;

    float* xout     = (float*)d_out;                 // [B,256,H,W] f32
    float* cost_out = xout + (size_t)BB*CC*HW;       // [B,32,H,W] f32

    k_prep_feat<<<3072, 256, 0, stream>>>(t_feat, s_feat, Tt, Ts);
    k_prep_w  <<<841,  256, 0, stream>>>(qw,qb,kw,kb,vw,vb,p1w,p2w,rw, Wqkv,bqkv,A1,A2,Ar);
    g_qkv     <<<1152, 256, 0, stream>>>(Tt, Ts, Wqkv, bqkv, X1, Vb);
    k_ca      <<<256,  768, 0, stream>>>(X1, Vb, directs, img_w, C1, Agg);
    g_conv1   <<<768,  256, 0, stream>>>(X1, Agg, A1, p1b, X2);
    g_conv2   <<<768,  128, 0, stream>>>(X2, A2, p2b, C1, cost_out);
    k_sm2     <<<96,   256, 0, stream>>>(cost_out, NC);
    g_final   <<<1536, 256, 0, stream>>>(Tt, NC, Ar, rb, xout);
}

// Round 5
// 145.941 us; speedup vs baseline: 5.6931x; 1.0480x over previous
//
#include <hip/hip_runtime.h>

#define BB 2
#define CC 256
#define CQ 64
#define DD 32
#define HH 64
#define WW 192
#define HW (HH*WW)     // 12288
#define NPIX (BB*HW)   // 24576

typedef __attribute__((ext_vector_type(8))) short bf16x8;
typedef __attribute__((ext_vector_type(4))) float f32x4;

__device__ __forceinline__ float b2f(ushort s){ return __uint_as_float(((uint)s)<<16); }
__device__ __forceinline__ ushort f2b(float f){
    uint u = __float_as_uint(f);
    return (ushort)((u + 0x7fffu + ((u>>16)&1u)) >> 16);
}
__device__ __forceinline__ float eluf(float v){ return v > 0.f ? v : (__expf(v)-1.f); }

// ---------- prep: f32 NCHW -> bf16 pixel-major [B*HW][256] ----------
__global__ __launch_bounds__(256) void k_prep_feat(
    const float* __restrict__ t_feat, const float* __restrict__ s_feat,
    ushort* __restrict__ Tt, ushort* __restrict__ Ts)
{
    int n = blockIdx.x*256 + threadIdx.x;   // B*HW*32
    int p  = n % HW;
    int r  = n / HW;
    int c8 = r % 32;
    int b  = r / 32;
    const float* tp = t_feat + ((size_t)(b*CC + c8*8))*HW + p;
    const float* sp = s_feat + ((size_t)(b*CC + c8*8))*HW + p;
    uint tu[4], su[4];
    #pragma unroll
    for (int j2=0;j2<4;++j2){
        tu[j2] = (uint)f2b(tp[(size_t)(2*j2)*HW])   | ((uint)f2b(tp[(size_t)(2*j2+1)*HW])<<16);
        su[j2] = (uint)f2b(sp[(size_t)(2*j2)*HW])   | ((uint)f2b(sp[(size_t)(2*j2+1)*HW])<<16);
    }
    size_t dst = ((size_t)(b*HW + p))*CC + c8*8;
    uint4 t4; t4.x=tu[0]; t4.y=tu[1]; t4.z=tu[2]; t4.w=tu[3];
    uint4 s4; s4.x=su[0]; s4.y=su[1]; s4.z=su[2]; s4.w=su[3];
    *(uint4*)(Tt + dst) = t4;
    *(uint4*)(Ts + dst) = s4;
}

// ---------- prep: weights -> bf16 GEMM-A layouts ----------
__global__ __launch_bounds__(256) void k_prep_w(
    const float* __restrict__ qw, const float* __restrict__ qb,
    const float* __restrict__ kw, const float* __restrict__ kb,
    const float* __restrict__ vw, const float* __restrict__ vb,
    const float* __restrict__ p1w, const float* __restrict__ p2w,
    const float* __restrict__ rw,
    ushort* __restrict__ Wqkv, float* __restrict__ bqkv,
    ushort* __restrict__ A1, ushort* __restrict__ A2, ushort* __restrict__ Ar)
{
    int id = blockIdx.x*256 + threadIdx.x;
    if (id < 49152) {                      // Wqkv [192][256]
        int o = id / 256, c = id % 256;
        float v = (o<64)? qw[o*256+c] : (o<128)? kw[(o-64)*256+c] : vw[(o-128)*256+c];
        Wqkv[id] = f2b(v);
    } else if (id < 49344) {               // bqkv [192]
        int o = id - 49152;
        bqkv[o] = (o<64)? qb[o] : (o<128)? kb[o-64] : vb[o-128];
    } else if (id < 49344+73728) {         // A1 [64][9*128], k = t*128+ci
        int i = id - 49344;
        int o = i/1152, r = i%1152, t = r/128, ci = r%128;
        A1[i] = f2b(p1w[(size_t)(o*128+ci)*9 + t]);
    } else if (id < 49344+73728+18432) {   // A2 [32][9*64]
        int i = id - (49344+73728);
        int o = i/576, r = i%576, t = r/64, ci = r%64;
        A2[i] = f2b(p2w[(size_t)(o*64+ci)*9 + t]);
    } else if (id < 49344+73728+18432+73728) {  // Ar [256][288]
        int i = id - (49344+73728+18432);
        Ar[i] = f2b(rw[i]);
    }
}

// ---------- G1: qkv conv1x1 as MFMA GEMM ----------
__global__ __launch_bounds__(256) void g_qkv(
    const ushort* __restrict__ Tt, const ushort* __restrict__ Ts,
    const ushort* __restrict__ Wqkv, const float* __restrict__ bqkv,
    ushort* __restrict__ X1, ushort* __restrict__ Vb)
{
    int wv = threadIdx.x >> 6;
    int lane = threadIdx.x & 63;
    int lm = lane & 15, lk = lane >> 4;
    int g  = blockIdx.x / 384;
    int n0 = (blockIdx.x % 384) * 64;
    const ushort* Bsrc = (g==0) ? Tt : Ts;
    const ushort* Ap = Wqkv + (size_t)(g*64 + wv*16 + lm)*CC + lk*8;
    const ushort* Bp = Bsrc + (size_t)n0*CC + lk*8;
    f32x4 acc[4];
    #pragma unroll
    for (int i=0;i<4;++i) acc[i] = (f32x4){0.f,0.f,0.f,0.f};
    for (int k0=0; k0<CC; k0+=32){
        bf16x8 a = *(const bf16x8*)(Ap + k0);
        #pragma unroll
        for (int nt=0; nt<4; ++nt){
            bf16x8 bb = *(const bf16x8*)(Bp + (size_t)(nt*16+lm)*CC + k0);
            acc[nt] = __builtin_amdgcn_mfma_f32_16x16x32_bf16(a, bb, acc[nt], 0,0,0);
        }
    }
    int ob = g*64 + wv*16 + lk*4;   // bias index base
    int ol = wv*16 + lk*4;          // channel within 64
    #pragma unroll
    for (int nt=0; nt<4; ++nt){
        int p = n0 + nt*16 + lm;
        uint u0 = (uint)f2b(acc[nt][0]+bqkv[ob])   | ((uint)f2b(acc[nt][1]+bqkv[ob+1])<<16);
        uint u1 = (uint)f2b(acc[nt][2]+bqkv[ob+2]) | ((uint)f2b(acc[nt][3]+bqkv[ob+3])<<16);
        ushort* dst;
        if (g==0)      dst = X1 + (size_t)p*128 + ol;        // q half
        else if (g==1) dst = X1 + (size_t)p*128 + 64 + ol;   // K half (persistent)
        else           dst = Vb + (size_t)p*64 + ol;
        *(uint2*)dst = make_uint2(u0, u1);
    }
}

// ---------- k_ca: cost + softmax + aggV ----------
// 512 blocks = (b, h, quarter); 384 threads; chunk-major LDS [c8][x] (conflict-free b128)
#define SVS 194   // padded x-stride (in 16B chunks) so c8 groups start 8 banks apart
__global__ __launch_bounds__(384) void k_ca(
    const ushort* __restrict__ X1, const ushort* __restrict__ Vb,
    const float* __restrict__ directs, const int* __restrict__ img_w_p,
    float* __restrict__ C1, ushort* __restrict__ Agg)
{
    __shared__ ushort sK[8*SVS*8];   // 24.8 KiB
    __shared__ ushort sV[8*SVS*8];   // 24.8 KiB
    __shared__ ushort sQ[8*48*8];    // 6 KiB
    __shared__ float  sC[32*48];     // 6 KiB
    int tid = threadIdx.x;
    int blk = blockIdx.x;
    int b   = blk >> 8;
    int rem = blk & 255;
    int h   = rem >> 2;
    int qi  = rem & 3;
    int w0  = qi * 48;
    size_t rowbase = (size_t)b*HW + (size_t)h*WW;

    for (int i = tid; i < 1536; i += 384){      // full K/V row, chunk-major
        int c8 = i / 192, x = i % 192;
        *(uint4*)&sK[(c8*SVS + x)*8] = *(const uint4*)(X1 + (rowbase+x)*128 + 64 + c8*8);
        *(uint4*)&sV[(c8*SVS + x)*8] = *(const uint4*)(Vb + (rowbase+x)*64 + c8*8);
    }
    {
        int c8 = tid / 48, wl = tid % 48;       // Q quarter-row
        *(uint4*)&sQ[(c8*48 + wl)*8] = *(const uint4*)(X1 + (rowbase+w0+wl)*128 + c8*8);
    }
    __syncthreads();

    int imw = img_w_p[0];
    float rel = (imw != 640) ? (640.0f/(float)imw) : 1.0f;
    float sf = 0.01f * rel * directs[b] * 191.0f;

    int wl  = tid % 48;
    int grp = tid / 48;          // 0..7
    int w   = w0 + wl;

    // ---- phase A: cost, 4 d's per thread ----
    {
        float qf[64];
        #pragma unroll
        for (int c8=0;c8<8;++c8){
            bf16x8 qv = *(const bf16x8*)&sQ[(c8*48+wl)*8];
            #pragma unroll
            for (int j=0;j<8;++j) qf[c8*8+j] = b2f((ushort)qv[j]);
        }
        #pragma unroll
        for (int j=0;j<4;++j){
            int d = grp*4 + j;
            float srcx = fminf(fmaxf((float)w + (float)d*sf, 0.f), 191.0f);
            int x0 = (int)floorf(srcx);
            int x1 = min(x0+1, 191);
            float fr = srcx - (float)x0;
            float s0 = 0.f, s1 = 0.f;
            #pragma unroll
            for (int c8=0;c8<8;++c8){
                bf16x8 k0v = *(const bf16x8*)&sK[(c8*SVS+x0)*8];
                bf16x8 k1v = *(const bf16x8*)&sK[(c8*SVS+x1)*8];
                #pragma unroll
                for (int jj=0;jj<8;++jj){
                    s0 += qf[c8*8+jj]*b2f((ushort)k0v[jj]);
                    s1 += qf[c8*8+jj]*b2f((ushort)k1v[jj]);
                }
            }
            sC[d*48 + wl] = (s0 + fr*(s1-s0)) * 0.125f;
        }
    }
    __syncthreads();

    // ---- phase B: softmax over d + coalesced C1 write ----
    if (tid < 48){
        float v[DD]; float m = -1e30f;
        #pragma unroll
        for (int d=0; d<DD; ++d){ v[d] = sC[d*48+tid]; m = fmaxf(m, v[d]); }
        float* cp = C1 + (rowbase + w0 + tid)*DD;
        #pragma unroll
        for (int d=0; d<DD; d+=4){
            f32x4 t4; t4[0]=v[d]; t4[1]=v[d+1]; t4[2]=v[d+2]; t4[3]=v[d+3];
            *(f32x4*)(cp + d) = t4;
        }
        float s = 0.f;
        #pragma unroll
        for (int d=0; d<DD; ++d){ v[d] = __expf(v[d]-m); s += v[d]; }
        float inv = 1.f/s;
        #pragma unroll
        for (int d=0; d<DD; ++d) sC[d*48+tid] = v[d]*inv;
    }
    __syncthreads();

    // ---- phase C: agg_v, 8 channels per thread ----
    {
        float agg[8];
        #pragma unroll
        for (int j=0;j<8;++j) agg[j]=0.f;
        for (int d=0; d<DD; ++d){
            float pd = sC[d*48 + wl];
            float srcx = fminf(fmaxf((float)w + (float)d*sf, 0.f), 191.0f);
            int x0 = (int)floorf(srcx);
            int x1 = min(x0+1, 191);
            float fr = srcx - (float)x0;
            float a1 = pd*fr, a0 = pd - a1;
            bf16x8 v0v = *(const bf16x8*)&sV[(grp*SVS+x0)*8];
            bf16x8 v1v = *(const bf16x8*)&sV[(grp*SVS+x1)*8];
            #pragma unroll
            for (int j=0;j<8;++j)
                agg[j] += a0*b2f((ushort)v0v[j]) + a1*b2f((ushort)v1v[j]);
        }
        uint u[4];
        #pragma unroll
        for (int j2=0;j2<4;++j2)
            u[j2] = (uint)f2b(agg[j2*2]) | ((uint)f2b(agg[j2*2+1])<<16);
        uint4 q4; q4.x=u[0]; q4.y=u[1]; q4.z=u[2]; q4.w=u[3];
        *(uint4*)(Agg + (rowbase + w)*64 + grp*8) = q4;
    }
}

// ---------- G2: conv3x3 p1 as LDS-staged implicit GEMM, ELU ----------
// 768 blocks x 256 thr; stage 3 rows x 34 px x 128 ch chunk-major; wave = 32m x 16n
__global__ __launch_bounds__(256) void g_conv1(
    const ushort* __restrict__ X1, const ushort* __restrict__ Agg,
    const ushort* __restrict__ A1, const float* __restrict__ p1b,
    ushort* __restrict__ X2)
{
    __shared__ ushort sB[3*16*34*8];   // 26.1 KiB  [(dh*16+c16)*34 + x]*8
    int tid = threadIdx.x;
    int wv = tid >> 6, lane = tid & 63;
    int lm = lane & 15, lk = lane >> 4;
    int n0 = blockIdx.x * 32;
    int b  = n0 / HW;
    int pl = n0 % HW;
    int h  = pl / WW, w0 = pl % WW;

    for (int i = tid; i < 1632; i += 256){
        int dh = i / 544, rem2 = i % 544;
        int c16 = rem2 / 34, x = rem2 % 34;
        int hh = h + dh - 1, wx = w0 + x - 1;
        uint4 val = make_uint4(0,0,0,0);
        if (hh >= 0 && hh < HH && wx >= 0 && wx < WW){
            size_t pix = (size_t)b*HW + (size_t)hh*WW + wx;
            val = (c16 < 8) ? *(const uint4*)(X1 + pix*128 + c16*8)
                            : *(const uint4*)(Agg + pix*64 + (c16-8)*8);
        }
        *(uint4*)&sB[((dh*16 + c16)*34 + x)*8] = val;
    }
    __syncthreads();

    int mw = wv & 1, nw = wv >> 1;
    const ushort* Ap = A1 + (size_t)(mw*32 + lm)*1152 + lk*8;
    f32x4 acc0 = {0.f,0.f,0.f,0.f}, acc1 = {0.f,0.f,0.f,0.f};
    int xb = nw*16 + lm;
    #pragma unroll
    for (int t=0; t<9; ++t){
        int dh = t/3, dw = t%3;
        #pragma unroll
        for (int c0=0; c0<128; c0+=32){
            bf16x8 bb = *(const bf16x8*)&sB[((dh*16 + (c0>>3)+lk)*34 + xb + dw)*8];
            bf16x8 a0 = *(const bf16x8*)(Ap + t*128 + c0);
            bf16x8 a1 = *(const bf16x8*)(Ap + (size_t)16*1152 + t*128 + c0);
            acc0 = __builtin_amdgcn_mfma_f32_16x16x32_bf16(a0, bb, acc0, 0,0,0);
            acc1 = __builtin_amdgcn_mfma_f32_16x16x32_bf16(a1, bb, acc1, 0,0,0);
        }
    }
    int pg = n0 + nw*16 + lm;
    int o0 = mw*32 + lk*4;
    {
        uint u0 = (uint)f2b(eluf(acc0[0]+p1b[o0]))   | ((uint)f2b(eluf(acc0[1]+p1b[o0+1]))<<16);
        uint u1 = (uint)f2b(eluf(acc0[2]+p1b[o0+2])) | ((uint)f2b(eluf(acc0[3]+p1b[o0+3]))<<16);
        *(uint2*)(X2 + (size_t)pg*64 + o0) = make_uint2(u0, u1);
        int o1 = o0 + 16;
        uint u2 = (uint)f2b(eluf(acc1[0]+p1b[o1]))   | ((uint)f2b(eluf(acc1[1]+p1b[o1+1]))<<16);
        uint u3 = (uint)f2b(eluf(acc1[2]+p1b[o1+2])) | ((uint)f2b(eluf(acc1[3]+p1b[o1+3]))<<16);
        *(uint2*)(X2 + (size_t)pg*64 + o1) = make_uint2(u2, u3);
    }
}

// ---------- G3: conv3x3 p2 + residual avg -> cost_out (LDS-staged) ----------
__global__ __launch_bounds__(256) void g_conv2(
    const ushort* __restrict__ X2, const ushort* __restrict__ A2,
    const float* __restrict__ p2b, const float* __restrict__ C1,
    float* __restrict__ cost_out)
{
    __shared__ ushort sB[3*8*34*8];   // 13 KiB
    int tid = threadIdx.x;
    int wv = tid >> 6, lane = tid & 63;
    int lm = lane & 15, lk = lane >> 4;
    int n0 = blockIdx.x * 32;
    int b  = n0 / HW;
    int pl = n0 % HW;
    int h  = pl / WW, w0 = pl % WW;

    for (int i = tid; i < 816; i += 256){
        int dh = i / 272, rem2 = i % 272;
        int c16 = rem2 / 34, x = rem2 % 34;
        int hh = h + dh - 1, wx = w0 + x - 1;
        uint4 val = make_uint4(0,0,0,0);
        if (hh >= 0 && hh < HH && wx >= 0 && wx < WW)
            val = *(const uint4*)(X2 + ((size_t)b*HW + (size_t)hh*WW + wx)*64 + c16*8);
        *(uint4*)&sB[((dh*8 + c16)*34 + x)*8] = val;
    }
    __syncthreads();

    int mw = wv & 1, nw = wv >> 1;
    const ushort* Ap = A2 + (size_t)(mw*16 + lm)*576 + lk*8;
    f32x4 acc = {0.f,0.f,0.f,0.f};
    int xb = nw*16 + lm;
    #pragma unroll
    for (int t=0; t<9; ++t){
        int dh = t/3, dw = t%3;
        #pragma unroll
        for (int c0=0; c0<64; c0+=32){
            bf16x8 bb = *(const bf16x8*)&sB[((dh*8 + (c0>>3)+lk)*34 + xb + dw)*8];
            bf16x8 a  = *(const bf16x8*)(Ap + t*64 + c0);
            acc = __builtin_amdgcn_mfma_f32_16x16x32_bf16(a, bb, acc, 0,0,0);
        }
    }
    int pg = n0 + nw*16 + lm;
    int pll = pg % HW;
    int o = mw*16 + lk*4;
    f32x4 cv = *(const f32x4*)(C1 + (size_t)pg*DD + o);
    #pragma unroll
    for (int j=0;j<4;++j)
        cost_out[((size_t)(b*DD + o + j))*HW + pll] = (cv[j] + acc[j] + p2b[o+j]) * 0.5f;
}

// ---------- softmax over D -> NC (bf16 pixel-major) ----------
__global__ __launch_bounds__(256) void k_sm2(
    const float* __restrict__ cost_out, ushort* __restrict__ NC)
{
    int n = blockIdx.x*256 + threadIdx.x;   // 24576
    int b = n / HW, pl = n % HW;
    const float* cp = cost_out + (size_t)b*DD*HW + pl;
    float v[DD]; float m = -1e30f;
    #pragma unroll
    for (int d=0; d<DD; ++d){ v[d] = cp[(size_t)d*HW]; m = fmaxf(m, v[d]); }
    float s = 0.f;
    #pragma unroll
    for (int d=0; d<DD; ++d){ v[d] = __expf(v[d]-m); s += v[d]; }
    float inv = 1.f/s;
    ushort* op = NC + (size_t)n*DD;
    #pragma unroll
    for (int d8=0; d8<4; ++d8){
        uint u[4];
        #pragma unroll
        for (int j2=0;j2<4;++j2)
            u[j2] = (uint)f2b(v[d8*8+j2*2]*inv) | ((uint)f2b(v[d8*8+j2*2+1]*inv)<<16);
        uint4 q4; q4.x=u[0]; q4.y=u[1]; q4.z=u[2]; q4.w=u[3];
        *(uint4*)(op + d8*8) = q4;
    }
}

// ---------- G4: final conv1x1 on concat(t_feat, nc2), ELU ----------
__global__ __launch_bounds__(256) void g_final(
    const ushort* __restrict__ Tt, const ushort* __restrict__ NC,
    const ushort* __restrict__ Ar, const float* __restrict__ rb,
    float* __restrict__ xout)
{
    int wv = threadIdx.x >> 6;
    int lane = threadIdx.x & 63;
    int lm = lane & 15, lk = lane >> 4;
    int mg = blockIdx.x / 384;
    int n0 = (blockIdx.x % 384) * 64;
    const ushort* Ap = Ar + (size_t)(mg*64 + wv*16 + lm)*288 + lk*8;
    f32x4 acc[4];
    #pragma unroll
    for (int i=0;i<4;++i) acc[i] = (f32x4){0.f,0.f,0.f,0.f};
    for (int k0=0; k0<288; k0+=32){
        bf16x8 a = *(const bf16x8*)(Ap + k0);
        #pragma unroll
        for (int nt=0; nt<4; ++nt){
            int p = n0 + nt*16 + lm;
            const ushort* src = (k0 < 256) ? (Tt + (size_t)p*CC + k0 + lk*8)
                                           : (NC + (size_t)p*DD + lk*8);
            bf16x8 bb = *(const bf16x8*)src;
            acc[nt] = __builtin_amdgcn_mfma_f32_16x16x32_bf16(a, bb, acc[nt], 0,0,0);
        }
    }
    int o = mg*64 + wv*16 + lk*4;
    #pragma unroll
    for (int nt=0; nt<4; ++nt){
        int p = n0 + nt*16 + lm;
        int b = p / HW, pl = p % HW;
        #pragma unroll
        for (int j=0;j<4;++j)
            xout[((size_t)(b*CC + o + j))*HW + pl] = eluf(acc[nt][j] + rb[o+j]);
    }
}

extern "C" void kernel_launch(void* const* d_in, const int* in_sizes, int n_in,
                              void* d_out, int out_size, void* d_ws, size_t ws_size,
                              hipStream_t stream)
{
    const float* t_feat = (const float*)d_in[0];
    const float* s_feat = (const float*)d_in[1];
    const float* directs= (const float*)d_in[2];
    const float* qw = (const float*)d_in[3];
    const float* qb = (const float*)d_in[4];
    const float* kw = (const float*)d_in[5];
    const float* kb = (const float*)d_in[6];
    const float* vw = (const float*)d_in[7];
    const float* vb = (const float*)d_in[8];
    const float* p1w= (const float*)d_in[9];
    const float* p1b= (const float*)d_in[10];
    const float* p2w= (const float*)d_in[11];
    const float* p2b= (const float*)d_in[12];
    const float* rw = (const float*)d_in[13];
    const float* rb = (const float*)d_in[14];
    const int* img_w= (const int*)d_in[15];

    // workspace layout (byte offsets, lifetime-aliased)
    char* wsb = (char*)d_ws;
    ushort* Tt   = (ushort*)(wsb + 0);           // 12,582,912 B  [NPIX][256] bf16
    char*  tsreg = wsb + 12582912;               // 12,582,912 B region
    ushort* Ts   = (ushort*)tsreg;               //   Ts (dead after g_qkv)
    ushort* X2   = (ushort*)tsreg;               //   X2 [NPIX][64] bf16 (3,145,728) aliases Ts
    float*  C1   = (float*)(tsreg + 3145728);    //   C1 [NPIX][32] f32 (3,145,728)
    ushort* Agg  = (ushort*)(tsreg + 6291456);   //   Agg [NPIX][64] bf16 (3,145,728)
    ushort* X1   = (ushort*)(wsb + 25165824);    // 6,291,456 B [NPIX][128] bf16 (q | K)
    ushort* Vb   = (ushort*)(wsb + 31457280);    // 3,145,728 B [NPIX][64] bf16
    ushort* NC   = (ushort*)(wsb + 31457280);    // aliases Vb after k_ca
    ushort* Wqkv = (ushort*)(wsb + 34603008);    // 98,304 B
    float*  bqkv = (float*) (wsb + 34701312);    // 768 B (pad to 1024)
    ushort* A1   = (ushort*)(wsb + 34702336);    // 147,456 B
    ushort* A2   = (ushort*)(wsb + 34849792);    // 36,864 B
    ushort* Ar   = (ushort*)(wsb + 34886656);    // 147,456 B -> end 35,034,112
    if (ws_size < 35034112) return;

    float* xout     = (float*)d_out;                 // [B,256,H,W] f32
    float* cost_out = xout + (size_t)BB*CC*HW;       // [B,32,H,W] f32

    k_prep_feat<<<3072, 256, 0, stream>>>(t_feat, s_feat, Tt, Ts);
    k_prep_w  <<<841,  256, 0, stream>>>(qw,qb,kw,kb,vw,vb,p1w,p2w,rw, Wqkv,bqkv,A1,A2,Ar);
    g_qkv     <<<1152, 256, 0, stream>>>(Tt, Ts, Wqkv, bqkv, X1, Vb);
    k_ca      <<<512,  384, 0, stream>>>(X1, Vb, directs, img_w, C1, Agg);
    g_conv1   <<<768,  256, 0, stream>>>(X1, Agg, A1, p1b, X2);
    g_conv2   <<<768,  256, 0, stream>>>(X2, A2, p2b, C1, cost_out);
    k_sm2     <<<96,   256, 0, stream>>>(cost_out, NC);
    g_final   <<<1536, 256, 0, stream>>>(Tt, NC, Ar, rb, xout);
}